// Round 1
// baseline (2850.050 us; speedup 1.0000x reference)
//
#include <hip/hip_runtime.h>
#include <math.h>

#define NTOK 1024
#define CT   768
#define CS   384
#define CP   16
#define NH   16
#define DH   48
#define NBLK 4
#define NL   8
#define NKEY 32
#define KTOT 40
#define SCALE_ 0.14433756729740643f   // 1/sqrt(48)

__device__ __forceinline__ float sigmoidf_(float x) {
    return 1.0f / (1.0f + expf(-x));
}

// ---------------------------------------------------------------------------
// Top-k spatial neighbours + local window indices.
// One block per token. 32 iterations of parallel argmin (tie -> lower index),
// matching jax.lax.top_k(-d2, 32) semantics.
// ---------------------------------------------------------------------------
__global__ __launch_bounds__(256)
void topk_kernel(const float* __restrict__ X, int* __restrict__ idx) {
    int n = blockIdx.x;
    int t = threadIdx.x;
    __shared__ float d2[NTOK];
    __shared__ float redv[256];
    __shared__ int   redi[256];

    float x0 = X[n * 3 + 0], x1 = X[n * 3 + 1], x2 = X[n * 3 + 2];
    for (int m = t; m < NTOK; m += 256) {
        float dx = x0 - X[m * 3 + 0];
        float dy = x1 - X[m * 3 + 1];
        float dz = x2 - X[m * 3 + 2];
        d2[m] = dx * dx + dy * dy + dz * dz;
    }
    if (t < NL) {
        int loc = n + t - NL / 2;
        loc = loc < 0 ? 0 : (loc > NTOK - 1 ? NTOK - 1 : loc);
        idx[n * KTOT + t] = loc;
    }
    __syncthreads();

    for (int it = 0; it < NKEY; ++it) {
        float bv = INFINITY;
        int bi = NTOK;
        for (int m = t; m < NTOK; m += 256) {
            float v = d2[m];
            if (v < bv) { bv = v; bi = m; }   // ascending m: keeps lowest index on ties
        }
        redv[t] = bv; redi[t] = bi;
        __syncthreads();
        for (int s = 128; s > 0; s >>= 1) {
            if (t < s) {
                float ov = redv[t + s]; int oi = redi[t + s];
                if (ov < redv[t] || (ov == redv[t] && oi < redi[t])) {
                    redv[t] = ov; redi[t] = oi;
                }
            }
            __syncthreads();
        }
        if (t == 0) {
            idx[n * KTOT + NL + it] = redi[0];
            d2[redi[0]] = INFINITY;
        }
        __syncthreads();
    }
}

// ---------------------------------------------------------------------------
// Row LayerNorm (no affine). One block per row.
// ---------------------------------------------------------------------------
__global__ __launch_bounds__(256)
void ln_kernel(const float* __restrict__ in, float* __restrict__ out, int C) {
    int row = blockIdx.x;
    int t = threadIdx.x;
    __shared__ float red[256];
    float vals[6];
    int cnt = 0;
    float s = 0.0f;
    for (int c = t; c < C; c += 256) { float v = in[row * C + c]; vals[cnt++] = v; s += v; }
    red[t] = s; __syncthreads();
    for (int st = 128; st > 0; st >>= 1) { if (t < st) red[t] += red[t + st]; __syncthreads(); }
    float mean = red[0] / C;
    __syncthreads();
    float s2 = 0.0f;
    for (int j = 0; j < cnt; ++j) { float d = vals[j] - mean; s2 += d * d; }
    red[t] = s2; __syncthreads();
    for (int st = 128; st > 0; st >>= 1) { if (t < st) red[t] += red[t + st]; __syncthreads(); }
    float rstd = rsqrtf(red[0] / C + 1e-5f);
    for (int j = 0; j < cnt; ++j) {
        int c = t + j * 256;
        out[row * C + c] = (vals[j] - mean) * rstd;
    }
}

// ---------------------------------------------------------------------------
// Generic tiled fp32 GEMM with fused epilogues.
// MODE 0: out = acc1 (+cbias[col])
// MODE 1: out = sigmoid(acc1 + cbias[col]) * aux[r,c] + acc2       (AdaLN)
// MODE 2: out = silu(acc1) * acc2                                  (SwiGLU)
// MODE 3: out[r,c] += sigmoid(aux[r,c]) * acc1                     (gated add)
// Tile 32x32, 256 threads, each thread does 4 rows x 1 col.
// ---------------------------------------------------------------------------
template <int MODE>
__global__ __launch_bounds__(256)
void mm_kernel(const float* __restrict__ A, const float* __restrict__ Again,
               const float* __restrict__ B1, const float* __restrict__ B2,
               const float* __restrict__ cbias, const float* __restrict__ aux,
               float* __restrict__ out, int M, int K, int N) {
    constexpr bool DUAL = (MODE == 1 || MODE == 2);
    __shared__ float As[32][33];
    __shared__ float Bs1[32][33];
    __shared__ float Bs2[32][33];

    int tid = threadIdx.x;
    int tx = tid & 31;        // col in tile
    int ty = tid >> 5;        // 0..7
    int col0 = blockIdx.x * 32;
    int row0 = blockIdx.y * 32;

    float acc1[4] = {0, 0, 0, 0};
    float acc2[4] = {0, 0, 0, 0};

    for (int k0 = 0; k0 < K; k0 += 32) {
        float gscale = (Again != nullptr) ? Again[k0 + tx] : 1.0f;
#pragma unroll
        for (int i = 0; i < 4; ++i) {
            int r = ty + 8 * i;
            As[r][tx] = A[(size_t)(row0 + r) * K + k0 + tx] * gscale;
            Bs1[r][tx] = B1[(size_t)(k0 + r) * N + col0 + tx];
            if (DUAL) Bs2[r][tx] = B2[(size_t)(k0 + r) * N + col0 + tx];
        }
        __syncthreads();
#pragma unroll
        for (int kk = 0; kk < 32; ++kk) {
            float b1 = Bs1[kk][tx];
            float b2 = DUAL ? Bs2[kk][tx] : 0.0f;
#pragma unroll
            for (int i = 0; i < 4; ++i) {
                float a = As[ty + 8 * i][kk];
                acc1[i] += a * b1;
                if (DUAL) acc2[i] += a * b2;
            }
        }
        __syncthreads();
    }

#pragma unroll
    for (int i = 0; i < 4; ++i) {
        int row = row0 + ty + 8 * i;
        int col = col0 + tx;
        size_t o = (size_t)row * N + col;
        if (MODE == 0) {
            float v = acc1[i] + (cbias ? cbias[col] : 0.0f);
            out[o] = v;
        } else if (MODE == 1) {
            out[o] = sigmoidf_(acc1[i] + cbias[col]) * aux[o] + acc2[i];
        } else if (MODE == 2) {
            float x = acc1[i];
            out[o] = x * sigmoidf_(x) * acc2[i];
        } else if (MODE == 3) {
            out[o] += sigmoidf_(aux[o]) * acc1[i];
        }
    }
}

// ---------------------------------------------------------------------------
// Pair bias: biasT[n][h][k] = (LN(Z[n, idx[n,k], :]; pg, pb) @ Wb)[h]
// One thread per (n,k) pair. Grid = 1024*40/256 = 160 blocks.
// ---------------------------------------------------------------------------
__global__ __launch_bounds__(256)
void pairbias_kernel(const float* __restrict__ Z, const int* __restrict__ idx,
                     const float* __restrict__ pg, const float* __restrict__ pb,
                     const float* __restrict__ Wb, float* __restrict__ biasT) {
    __shared__ float wb[16][16];
    __shared__ float pgs[16], pbs[16];
    int t = threadIdx.x;
    wb[t >> 4][t & 15] = Wb[t];
    if (t < 16) { pgs[t] = pg[t]; pbs[t] = pb[t]; }
    __syncthreads();

    int task = blockIdx.x * 256 + t;
    int n = task / KTOT, k = task % KTOT;
    int m = idx[task];
    const float* z = Z + ((size_t)n * NTOK + m) * CP;
    float v[16];
    float s = 0.0f;
#pragma unroll
    for (int c = 0; c < 16; ++c) { v[c] = z[c]; s += v[c]; }
    float mean = s * (1.0f / 16.0f);
    float s2 = 0.0f;
#pragma unroll
    for (int c = 0; c < 16; ++c) { float d = v[c] - mean; s2 += d * d; }
    float rstd = rsqrtf(s2 * (1.0f / 16.0f) + 1e-5f);
#pragma unroll
    for (int c = 0; c < 16; ++c) v[c] = (v[c] - mean) * rstd * pgs[c] + pbs[c];
#pragma unroll
    for (int h = 0; h < 16; ++h) {
        float a = 0.0f;
#pragma unroll
        for (int c = 0; c < 16; ++c) a += v[c] * wb[c][h];
        biasT[((size_t)n * NH + h) * KTOT + k] = a;
    }
}

// ---------------------------------------------------------------------------
// Attention: one block per token. scores -> softmax -> PV, gated by
// sigmoid(gfull). Writes o2[n][h*DH+d].
// ---------------------------------------------------------------------------
__global__ __launch_bounds__(256)
void attn_kernel(const float* __restrict__ qf, const float* __restrict__ kf,
                 const float* __restrict__ vf, const float* __restrict__ biasT,
                 const float* __restrict__ gfull, const int* __restrict__ idx,
                 float* __restrict__ o2) {
    int n = blockIdx.x;
    int t = threadIdx.x;
    __shared__ float sc[NH][KTOT];
    __shared__ int sidx[KTOT];
    if (t < KTOT) sidx[t] = idx[n * KTOT + t];
    __syncthreads();

    for (int task = t; task < NH * KTOT; task += 256) {
        int h = task / KTOT, k = task % KTOT;
        const float* q = qf + (size_t)n * CT + h * DH;
        const float* kp = kf + (size_t)sidx[k] * CT + h * DH;
        float s = 0.0f;
#pragma unroll
        for (int d = 0; d < DH; ++d) s += q[d] * kp[d];
        sc[h][k] = s * SCALE_ + biasT[((size_t)n * NH + h) * KTOT + k];
    }
    __syncthreads();

    if (t < NH) {
        float mx = -INFINITY;
#pragma unroll
        for (int k = 0; k < KTOT; ++k) mx = fmaxf(mx, sc[t][k]);
        float sum = 0.0f;
#pragma unroll
        for (int k = 0; k < KTOT; ++k) { float e = expf(sc[t][k] - mx); sc[t][k] = e; sum += e; }
        float inv = 1.0f / sum;
#pragma unroll
        for (int k = 0; k < KTOT; ++k) sc[t][k] *= inv;
    }
    __syncthreads();

    for (int task = t; task < CT; task += 256) {
        int h = task / DH, d = task % DH;
        float acc = 0.0f;
#pragma unroll
        for (int k = 0; k < KTOT; ++k)
            acc += sc[h][k] * vf[(size_t)sidx[k] * CT + h * DH + d];
        float g = gfull[(size_t)n * CT + task];
        o2[(size_t)n * CT + task] = sigmoidf_(g) * acc;
    }
}

// ---------------------------------------------------------------------------
// Host orchestration
// ---------------------------------------------------------------------------
extern "C" void kernel_launch(void* const* d_in, const int* in_sizes, int n_in,
                              void* d_out, int out_size, void* d_ws, size_t ws_size,
                              hipStream_t stream) {
    const float* A_I  = (const float*)d_in[0];
    const float* S_I  = (const float*)d_in[1];
    const float* Z_II = (const float*)d_in[2];
    const float* X_L  = (const float*)d_in[3];
    // d_in[4] = f (unused by reference)
    const float* aln1_sln_g = (const float*)d_in[5];
    const float* aln1_sw    = (const float*)d_in[6];
    const float* aln1_sb    = (const float*)d_in[7];
    const float* aln1_shw   = (const float*)d_in[8];
    const float* Wq  = (const float*)d_in[9];
    const float* bq  = (const float*)d_in[10];
    const float* Wk  = (const float*)d_in[11];
    const float* Wv  = (const float*)d_in[12];
    const float* pair_ln_g = (const float*)d_in[13];
    const float* pair_ln_b = (const float*)d_in[14];
    const float* Wb  = (const float*)d_in[15];
    const float* Wg  = (const float*)d_in[16];
    const float* Wo  = (const float*)d_in[17];
    const float* sg_w = (const float*)d_in[18];
    const float* sg_b = (const float*)d_in[19];
    const float* aln2_sln_g = (const float*)d_in[20];
    const float* aln2_sw    = (const float*)d_in[21];
    const float* aln2_sb    = (const float*)d_in[22];
    const float* aln2_shw   = (const float*)d_in[23];
    const float* t_w1 = (const float*)d_in[24];
    const float* t_w2 = (const float*)d_in[25];
    const float* t_w3 = (const float*)d_in[26];
    const float* tsg_w = (const float*)d_in[27];
    const float* tsg_b = (const float*)d_in[28];

    float* A = (float*)d_out;   // residual stream lives in d_out

    // workspace layout
    char* ws = (char*)d_ws;
    size_t off = 0;
    auto alloc = [&](size_t bytes) {
        void* p = ws + off;
        off += (bytes + 255) & ~(size_t)255;
        return p;
    };
    int*   idx   = (int*)  alloc(NTOK * KTOT * 4);
    float* LNS   = (float*)alloc((size_t)NTOK * CS * 4);
    float* LNA   = (float*)alloc((size_t)NTOK * CT * 4);
    float* an    = (float*)alloc((size_t)NTOK * CT * 4);
    float* qf    = (float*)alloc((size_t)NTOK * CT * 4);
    float* kfull = (float*)alloc((size_t)NTOK * CT * 4);
    float* vfull = (float*)alloc((size_t)NTOK * CT * 4);
    float* gfull = (float*)alloc((size_t)NTOK * CT * 4);
    float* sgate = (float*)alloc((size_t)NTOK * CT * 4);
    float* biasT = (float*)alloc((size_t)NTOK * NH * KTOT * 4);
    float* o2    = (float*)alloc((size_t)NTOK * CT * 4);
    float* hb    = (float*)alloc((size_t)NTOK * 2 * CT * 4);
    (void)ws_size; (void)in_sizes; (void)n_in; (void)out_size;

    // A <- A_I
    hipMemcpyAsync(A, A_I, (size_t)NTOK * CT * 4, hipMemcpyDeviceToDevice, stream);

    topk_kernel<<<NTOK, 256, 0, stream>>>(X_L, idx);
    ln_kernel<<<NTOK, 256, 0, stream>>>(S_I, LNS, CS);

    dim3 g768(CT / 32, NTOK / 32);       // N=768
    dim3 g1536(2 * CT / 32, NTOK / 32);  // N=1536

    for (int i = 0; i < NBLK; ++i) {
        const size_t wCT  = (size_t)i * CT * CT;
        const size_t wCS  = (size_t)i * CS * CT;
        const size_t wT   = (size_t)i * CT * 2 * CT;
        const size_t wT3  = (size_t)i * 2 * CT * CT;

        // ---- LocalAttentionPairBias ----
        ln_kernel<<<NTOK, 256, 0, stream>>>(A, LNA, CT);
        mm_kernel<1><<<g768, 256, 0, stream>>>(LNS, aln1_sln_g + (size_t)i * CS,
                                               aln1_sw + wCS, aln1_shw + wCS,
                                               aln1_sb + (size_t)i * CT, LNA, an,
                                               NTOK, CS, CT);
        mm_kernel<0><<<g768, 256, 0, stream>>>(an, nullptr, Wq + wCT, nullptr,
                                               bq + (size_t)i * CT, nullptr, qf,
                                               NTOK, CT, CT);
        mm_kernel<0><<<g768, 256, 0, stream>>>(an, nullptr, Wk + wCT, nullptr,
                                               nullptr, nullptr, kfull, NTOK, CT, CT);
        mm_kernel<0><<<g768, 256, 0, stream>>>(an, nullptr, Wv + wCT, nullptr,
                                               nullptr, nullptr, vfull, NTOK, CT, CT);
        mm_kernel<0><<<g768, 256, 0, stream>>>(an, nullptr, Wg + wCT, nullptr,
                                               nullptr, nullptr, gfull, NTOK, CT, CT);
        mm_kernel<0><<<g768, 256, 0, stream>>>(S_I, nullptr, sg_w + wCS, nullptr,
                                               sg_b + (size_t)i * CT, nullptr, sgate,
                                               NTOK, CS, CT);
        pairbias_kernel<<<NTOK * KTOT / 256, 256, 0, stream>>>(
            Z_II, idx, pair_ln_g + (size_t)i * CP, pair_ln_b + (size_t)i * CP,
            Wb + (size_t)i * CP * NH, biasT);
        attn_kernel<<<NTOK, 256, 0, stream>>>(qf, kfull, vfull, biasT, gfull, idx, o2);
        mm_kernel<3><<<g768, 256, 0, stream>>>(o2, nullptr, Wo + wCT, nullptr,
                                               nullptr, sgate, A, NTOK, CT, CT);

        // ---- ConditionedTransitionBlock ----
        ln_kernel<<<NTOK, 256, 0, stream>>>(A, LNA, CT);
        mm_kernel<1><<<g768, 256, 0, stream>>>(LNS, aln2_sln_g + (size_t)i * CS,
                                               aln2_sw + wCS, aln2_shw + wCS,
                                               aln2_sb + (size_t)i * CT, LNA, an,
                                               NTOK, CS, CT);
        mm_kernel<0><<<g768, 256, 0, stream>>>(S_I, nullptr, tsg_w + wCS, nullptr,
                                               tsg_b + (size_t)i * CT, nullptr, sgate,
                                               NTOK, CS, CT);
        mm_kernel<2><<<g1536, 256, 0, stream>>>(an, nullptr, t_w1 + wT, t_w2 + wT,
                                                nullptr, nullptr, hb, NTOK, CT, 2 * CT);
        mm_kernel<3><<<g768, 256, 0, stream>>>(hb, nullptr, t_w3 + wT3, nullptr,
                                               nullptr, sgate, A, NTOK, 2 * CT, CT);
    }
}

// Round 2
// 762.479 us; speedup vs baseline: 3.7379x; 3.7379x over previous
//
#include <hip/hip_runtime.h>
#include <hip/hip_bf16.h>
#include <math.h>
#include <stdint.h>

#define NTOK 1024
#define CT   768
#define CS   384
#define CP   16
#define NH   16
#define DH   48
#define NBLK 4
#define NL   8
#define NKEY 32
#define KTOT 40
#define SCALE_ 0.14433756729740643f   // 1/sqrt(48)

typedef __attribute__((ext_vector_type(8))) short short8;
typedef __attribute__((ext_vector_type(4))) float f32x4;

#define AS1 __attribute__((address_space(1)))
#define AS3 __attribute__((address_space(3)))

__device__ __forceinline__ float sigmoidf_(float x) {
    return 1.0f / (1.0f + expf(-x));
}

// async global(16B/lane) -> LDS (wave-uniform base + lane*16)
__device__ __forceinline__ void gl_lds16(const void* g, void* l) {
    __builtin_amdgcn_global_load_lds((const AS1 void*)(uintptr_t)g,
                                     (AS3 void*)(uintptr_t)l, 16, 0, 0);
}

// ---------------------------------------------------------------------------
// Top-k spatial neighbours + local window indices (matches jax.lax.top_k ties)
// ---------------------------------------------------------------------------
__global__ __launch_bounds__(256)
void topk_kernel(const float* __restrict__ X, int* __restrict__ idx) {
    int n = blockIdx.x;
    int t = threadIdx.x;
    __shared__ float d2[NTOK];
    __shared__ float redv[256];
    __shared__ int   redi[256];

    float x0 = X[n * 3 + 0], x1 = X[n * 3 + 1], x2 = X[n * 3 + 2];
    for (int m = t; m < NTOK; m += 256) {
        float dx = x0 - X[m * 3 + 0];
        float dy = x1 - X[m * 3 + 1];
        float dz = x2 - X[m * 3 + 2];
        d2[m] = dx * dx + dy * dy + dz * dz;
    }
    if (t < NL) {
        int loc = n + t - NL / 2;
        loc = loc < 0 ? 0 : (loc > NTOK - 1 ? NTOK - 1 : loc);
        idx[n * KTOT + t] = loc;
    }
    __syncthreads();

    for (int it = 0; it < NKEY; ++it) {
        float bv = INFINITY;
        int bi = NTOK;
        for (int m = t; m < NTOK; m += 256) {
            float v = d2[m];
            if (v < bv) { bv = v; bi = m; }
        }
        redv[t] = bv; redi[t] = bi;
        __syncthreads();
        for (int s = 128; s > 0; s >>= 1) {
            if (t < s) {
                float ov = redv[t + s]; int oi = redi[t + s];
                if (ov < redv[t] || (ov == redv[t] && oi < redi[t])) {
                    redv[t] = ov; redi[t] = oi;
                }
            }
            __syncthreads();
        }
        if (t == 0) {
            idx[n * KTOT + NL + it] = redi[0];
            d2[redi[0]] = INFINITY;
        }
        __syncthreads();
    }
}

// ---------------------------------------------------------------------------
// Row LayerNorm (no affine), fp32 out
// ---------------------------------------------------------------------------
__global__ __launch_bounds__(256)
void ln_kernel(const float* __restrict__ in, float* __restrict__ out, int C) {
    int row = blockIdx.x;
    int t = threadIdx.x;
    __shared__ float red[256];
    float vals[6];
    int cnt = 0;
    float s = 0.0f;
    for (int c = t; c < C; c += 256) { float v = in[row * C + c]; vals[cnt++] = v; s += v; }
    red[t] = s; __syncthreads();
    for (int st = 128; st > 0; st >>= 1) { if (t < st) red[t] += red[t + st]; __syncthreads(); }
    float mean = red[0] / C;
    __syncthreads();
    float s2 = 0.0f;
    for (int j = 0; j < cnt; ++j) { float d = vals[j] - mean; s2 += d * d; }
    red[t] = s2; __syncthreads();
    for (int st = 128; st > 0; st >>= 1) { if (t < st) red[t] += red[t + st]; __syncthreads(); }
    float rstd = rsqrtf(red[0] / C + 1e-5f);
    for (int j = 0; j < cnt; ++j) {
        int c = t + j * 256;
        out[row * C + c] = (vals[j] - mean) * rstd;
    }
}

// ---------------------------------------------------------------------------
// Weight convert + transpose: fp32 [K][N] -> bf16 [N][K]; up to 14 matrices
// per call via descriptor table (one launch per transformer block).
// ---------------------------------------------------------------------------
struct ConvDesc { const float* src; __hip_bfloat16* dst; int K; int N; int tstart; };
struct ConvTable { ConvDesc e[14]; };

__global__ __launch_bounds__(256)
void convT_kernel(ConvTable tab) {
    int b = blockIdx.x;
    int ei = 0;
#pragma unroll
    for (int j = 1; j < 14; ++j) if (b >= tab.e[j].tstart) ei = j;
    ConvDesc d = tab.e[ei];
    int tt = b - d.tstart;
    int ntn = d.N / 32;
    int k0 = (tt / ntn) * 32, n0 = (tt % ntn) * 32;
    __shared__ float s[32][33];
    int tx = threadIdx.x & 31, ty = threadIdx.x >> 5;
#pragma unroll
    for (int i = 0; i < 4; ++i)
        s[ty + 8 * i][tx] = d.src[(size_t)(k0 + ty + 8 * i) * d.N + n0 + tx];
    __syncthreads();
#pragma unroll
    for (int i = 0; i < 4; ++i)
        d.dst[(size_t)(n0 + ty + 8 * i) * d.K + k0 + tx] = __float2bfloat16(s[tx][ty + 8 * i]);
}

// ---------------------------------------------------------------------------
// Small prep kernels
// ---------------------------------------------------------------------------
__global__ __launch_bounds__(256)
void biasprep_kernel(const float* __restrict__ bq, const float* __restrict__ sg_b,
                     const float* __restrict__ tsg_b, float* __restrict__ qb,
                     float* __restrict__ sb2) {
    int t = blockIdx.x * 256 + threadIdx.x;
    if (t < NBLK * 3072) {
        int i = t / 3072, c = t % 3072;
        qb[t] = (c < 768) ? bq[i * 768 + c] : 0.0f;
    }
    if (t < NBLK * 1536) {
        int i = t / 1536, c = t % 1536;
        sb2[t] = (c < 768) ? sg_b[i * 768 + c] : tsg_b[i * 768 + c - 768];
    }
}

// snb[j][n][c] = bf16(LNS[n][c] * g_j[c]); j=2i -> aln1 of block i, j=2i+1 -> aln2
__global__ __launch_bounds__(256)
void snb_kernel(const float* __restrict__ LNS, const float* __restrict__ g1,
                const float* __restrict__ g2, __hip_bfloat16* __restrict__ snb) {
    int t = blockIdx.x * 256 + threadIdx.x;
    int j = t / (NTOK * CS);
    int rc = t % (NTOK * CS);
    int c = rc % CS;
    const float* g = ((j & 1) ? g2 : g1) + (j >> 1) * CS;
    snb[t] = __float2bfloat16(LNS[rc] * g[c]);
}

__global__ __launch_bounds__(256)
void tobf_kernel(const float* __restrict__ in, __hip_bfloat16* __restrict__ out) {
    int t = blockIdx.x * 256 + threadIdx.x;
    out[t] = __float2bfloat16(in[t]);
}

// ---------------------------------------------------------------------------
// bf16 MFMA GEMM, 64x64 tile, BK=32, 4 waves (2x2), each wave 32x32.
// A: [M][K] bf16 row-major. B1/B2: [N][K] bf16 (pre-transposed).
// MODE 0: outf = acc1 + cbias[col]                       (fp32 out)
// MODE 1: outb = bf16( sigmoid(acc1+cbias)*aux + acc2 )  (AdaLN)
// MODE 2: outb = bf16( silu(acc1) * acc2 )               (SwiGLU)
// MODE 3: outf += sigmoid(aux) * acc1                    (gated residual)
// ---------------------------------------------------------------------------
template <int MODE>
__global__ __launch_bounds__(256)
void gemm_kernel(const __hip_bfloat16* __restrict__ A,
                 const __hip_bfloat16* __restrict__ B1,
                 const __hip_bfloat16* __restrict__ B2,
                 const float* __restrict__ cbias,
                 const float* __restrict__ aux, int ld_aux,
                 float* __restrict__ outf, __hip_bfloat16* __restrict__ outb,
                 int K, int N, int ldo) {
    constexpr bool DUAL = (MODE == 1 || MODE == 2);
    __shared__ __hip_bfloat16 As[64 * 32];
    __shared__ __hip_bfloat16 Bs[64 * 32];
    __shared__ __hip_bfloat16 Bs2[DUAL ? 64 * 32 : 16];

    const int tid = threadIdx.x;
    const int lane = tid & 63;
    const int wid = tid >> 6;
    const int wr = wid >> 1, wc = wid & 1;
    const int row0 = blockIdx.y * 64;
    const int col0 = blockIdx.x * 64;

    // staging: each wave stages a 16-row chunk (1 KB) per tile
    const int srow = wid * 16 + (lane >> 2);
    const int selem = (lane & 3) * 8;
    const __hip_bfloat16* ag = A + (size_t)(row0 + srow) * K + selem;
    const __hip_bfloat16* bg = B1 + (size_t)(col0 + srow) * K + selem;
    const __hip_bfloat16* bg2 = DUAL ? (B2 + (size_t)(col0 + srow) * K + selem) : nullptr;
    char* alds = (char*)As + wid * 1024;
    char* blds = (char*)Bs + wid * 1024;
    char* blds2 = (char*)Bs2 + wid * 1024;

    f32x4 acc[2][2];
    f32x4 acc2[2][2];
#pragma unroll
    for (int i = 0; i < 2; ++i)
#pragma unroll
        for (int j = 0; j < 2; ++j) {
            acc[i][j] = (f32x4){0.f, 0.f, 0.f, 0.f};
            acc2[i][j] = (f32x4){0.f, 0.f, 0.f, 0.f};
        }

    const int rA0 = ((wr * 2 + 0) * 16 + (lane & 15)) * 32 + (lane >> 4) * 8;
    const int rA1 = ((wr * 2 + 1) * 16 + (lane & 15)) * 32 + (lane >> 4) * 8;
    const int cB0 = ((wc * 2 + 0) * 16 + (lane & 15)) * 32 + (lane >> 4) * 8;
    const int cB1 = ((wc * 2 + 1) * 16 + (lane & 15)) * 32 + (lane >> 4) * 8;

    for (int k0 = 0; k0 < K; k0 += 32) {
        gl_lds16(ag, alds);
        gl_lds16(bg, blds);
        if (DUAL) gl_lds16(bg2, blds2);
        ag += 32; bg += 32; if (DUAL) bg2 += 32;
        __syncthreads();
        short8 a0 = *(const short8*)&As[rA0];
        short8 a1 = *(const short8*)&As[rA1];
        short8 b0 = *(const short8*)&Bs[cB0];
        short8 b1 = *(const short8*)&Bs[cB1];
        acc[0][0] = __builtin_amdgcn_mfma_f32_16x16x32_bf16(a0, b0, acc[0][0], 0, 0, 0);
        acc[0][1] = __builtin_amdgcn_mfma_f32_16x16x32_bf16(a0, b1, acc[0][1], 0, 0, 0);
        acc[1][0] = __builtin_amdgcn_mfma_f32_16x16x32_bf16(a1, b0, acc[1][0], 0, 0, 0);
        acc[1][1] = __builtin_amdgcn_mfma_f32_16x16x32_bf16(a1, b1, acc[1][1], 0, 0, 0);
        if (DUAL) {
            short8 c0 = *(const short8*)&Bs2[cB0];
            short8 c1 = *(const short8*)&Bs2[cB1];
            acc2[0][0] = __builtin_amdgcn_mfma_f32_16x16x32_bf16(a0, c0, acc2[0][0], 0, 0, 0);
            acc2[0][1] = __builtin_amdgcn_mfma_f32_16x16x32_bf16(a0, c1, acc2[0][1], 0, 0, 0);
            acc2[1][0] = __builtin_amdgcn_mfma_f32_16x16x32_bf16(a1, c0, acc2[1][0], 0, 0, 0);
            acc2[1][1] = __builtin_amdgcn_mfma_f32_16x16x32_bf16(a1, c1, acc2[1][1], 0, 0, 0);
        }
        __syncthreads();
    }

#pragma unroll
    for (int mi = 0; mi < 2; ++mi)
#pragma unroll
        for (int ni = 0; ni < 2; ++ni) {
            f32x4 v1 = acc[mi][ni];
            f32x4 v2 = acc2[mi][ni];
            int col = col0 + wc * 32 + ni * 16 + (lane & 15);
            int rbase = row0 + wr * 32 + mi * 16 + (lane >> 4) * 4;
#pragma unroll
            for (int r = 0; r < 4; ++r) {
                int row = rbase + r;
                size_t o = (size_t)row * ldo + col;
                if (MODE == 0) {
                    outf[o] = v1[r] + (cbias ? cbias[col] : 0.0f);
                } else if (MODE == 1) {
                    float g = sigmoidf_(v1[r] + cbias[col]);
                    outb[o] = __float2bfloat16(g * aux[(size_t)row * ld_aux + col] + v2[r]);
                } else if (MODE == 2) {
                    float x = v1[r];
                    outb[o] = __float2bfloat16(x * sigmoidf_(x) * v2[r]);
                } else {
                    outf[o] += sigmoidf_(aux[(size_t)row * ld_aux + col]) * v1[r];
                }
            }
        }
}

// ---------------------------------------------------------------------------
// Pair bias: biasT[n][h][k] = (LN(Z[n, idx[n,k], :]; pg, pb) @ Wb)[h]
// ---------------------------------------------------------------------------
__global__ __launch_bounds__(256)
void pairbias_kernel(const float* __restrict__ Z, const int* __restrict__ idx,
                     const float* __restrict__ pg, const float* __restrict__ pb,
                     const float* __restrict__ Wb, float* __restrict__ biasT) {
    __shared__ float wb[16][16];
    __shared__ float pgs[16], pbs[16];
    int t = threadIdx.x;
    wb[t >> 4][t & 15] = Wb[t];
    if (t < 16) { pgs[t] = pg[t]; pbs[t] = pb[t]; }
    __syncthreads();

    int task = blockIdx.x * 256 + t;
    int n = task / KTOT, k = task % KTOT;
    int m = idx[task];
    const float* z = Z + ((size_t)n * NTOK + m) * CP;
    float v[16];
    float s = 0.0f;
#pragma unroll
    for (int c = 0; c < 16; ++c) { v[c] = z[c]; s += v[c]; }
    float mean = s * (1.0f / 16.0f);
    float s2 = 0.0f;
#pragma unroll
    for (int c = 0; c < 16; ++c) { float d = v[c] - mean; s2 += d * d; }
    float rstd = rsqrtf(s2 * (1.0f / 16.0f) + 1e-5f);
#pragma unroll
    for (int c = 0; c < 16; ++c) v[c] = (v[c] - mean) * rstd * pgs[c] + pbs[c];
#pragma unroll
    for (int h = 0; h < 16; ++h) {
        float a = 0.0f;
#pragma unroll
        for (int c = 0; c < 16; ++c) a += v[c] * wb[c][h];
        biasT[((size_t)n * NH + h) * KTOT + k] = a;
    }
}

// ---------------------------------------------------------------------------
// Attention on combined qkvg fp32 buffer [1024][3072]: q|k|v|g
// ---------------------------------------------------------------------------
__global__ __launch_bounds__(256)
void attn_kernel(const float* __restrict__ qkvg, const float* __restrict__ biasT,
                 const int* __restrict__ idx, __hip_bfloat16* __restrict__ o2) {
    int n = blockIdx.x;
    int t = threadIdx.x;
    __shared__ float sc[NH][KTOT];
    __shared__ int sidx[KTOT];
    if (t < KTOT) sidx[t] = idx[n * KTOT + t];
    __syncthreads();

    for (int task = t; task < NH * KTOT; task += 256) {
        int h = task / KTOT, k = task % KTOT;
        const float* q = qkvg + (size_t)n * 3072 + h * DH;
        const float* kp = qkvg + (size_t)sidx[k] * 3072 + 768 + h * DH;
        float s = 0.0f;
#pragma unroll
        for (int d = 0; d < DH; ++d) s += q[d] * kp[d];
        sc[h][k] = s * SCALE_ + biasT[((size_t)n * NH + h) * KTOT + k];
    }
    __syncthreads();

    if (t < NH) {
        float mx = -INFINITY;
#pragma unroll
        for (int k = 0; k < KTOT; ++k) mx = fmaxf(mx, sc[t][k]);
        float sum = 0.0f;
#pragma unroll
        for (int k = 0; k < KTOT; ++k) { float e = expf(sc[t][k] - mx); sc[t][k] = e; sum += e; }
        float inv = 1.0f / sum;
#pragma unroll
        for (int k = 0; k < KTOT; ++k) sc[t][k] *= inv;
    }
    __syncthreads();

    for (int task = t; task < CT; task += 256) {
        int h = task / DH, d = task % DH;
        float acc = 0.0f;
#pragma unroll
        for (int k = 0; k < KTOT; ++k)
            acc += sc[h][k] * qkvg[(size_t)sidx[k] * 3072 + 1536 + h * DH + d];
        float g = qkvg[(size_t)n * 3072 + 2304 + task];
        o2[(size_t)n * CT + task] = __float2bfloat16(sigmoidf_(g) * acc);
    }
}

// ---------------------------------------------------------------------------
// Host orchestration
// ---------------------------------------------------------------------------
extern "C" void kernel_launch(void* const* d_in, const int* in_sizes, int n_in,
                              void* d_out, int out_size, void* d_ws, size_t ws_size,
                              hipStream_t stream) {
    const float* A_I  = (const float*)d_in[0];
    const float* S_I  = (const float*)d_in[1];
    const float* Z_II = (const float*)d_in[2];
    const float* X_L  = (const float*)d_in[3];
    const float* aln1_sln_g = (const float*)d_in[5];
    const float* aln1_sw    = (const float*)d_in[6];
    const float* aln1_sb    = (const float*)d_in[7];
    const float* aln1_shw   = (const float*)d_in[8];
    const float* Wq  = (const float*)d_in[9];
    const float* bq  = (const float*)d_in[10];
    const float* Wk  = (const float*)d_in[11];
    const float* Wv  = (const float*)d_in[12];
    const float* pair_ln_g = (const float*)d_in[13];
    const float* pair_ln_b = (const float*)d_in[14];
    const float* Wbp = (const float*)d_in[15];
    const float* Wg  = (const float*)d_in[16];
    const float* Wo  = (const float*)d_in[17];
    const float* sg_w = (const float*)d_in[18];
    const float* sg_b = (const float*)d_in[19];
    const float* aln2_sln_g = (const float*)d_in[20];
    const float* aln2_sw    = (const float*)d_in[21];
    const float* aln2_sb    = (const float*)d_in[22];
    const float* aln2_shw   = (const float*)d_in[23];
    const float* t_w1 = (const float*)d_in[24];
    const float* t_w2 = (const float*)d_in[25];
    const float* t_w3 = (const float*)d_in[26];
    const float* tsg_w = (const float*)d_in[27];
    const float* tsg_b = (const float*)d_in[28];
    (void)in_sizes; (void)n_in; (void)out_size;

    float* A = (float*)d_out;

    char* ws = (char*)d_ws;
    size_t off = 0;
    auto alloc = [&](size_t bytes) {
        void* p = ws + off;
        off += (bytes + 255) & ~(size_t)255;
        return p;
    };
    int*   idx    = (int*)  alloc(NTOK * KTOT * 4);
    float* LNS    = (float*)alloc((size_t)NTOK * CS * 4);
    float* LNA    = (float*)alloc((size_t)NTOK * CT * 4);
    __hip_bfloat16* S_bf = (__hip_bfloat16*)alloc((size_t)NTOK * CS * 2);
    __hip_bfloat16* snb  = (__hip_bfloat16*)alloc((size_t)8 * NTOK * CS * 2);
    __hip_bfloat16* an   = (__hip_bfloat16*)alloc((size_t)NTOK * CT * 2);
    float* qkvg   = (float*)alloc((size_t)NTOK * 3072 * 4);
    float* sg2    = (float*)alloc((size_t)NTOK * 1536 * 4);
    float* biasT  = (float*)alloc((size_t)NTOK * NH * KTOT * 4);
    __hip_bfloat16* o2 = (__hip_bfloat16*)alloc((size_t)NTOK * CT * 2);
    __hip_bfloat16* hb = (__hip_bfloat16*)alloc((size_t)NTOK * 2 * CT * 2);
    float* qkvgbias = (float*)alloc((size_t)NBLK * 3072 * 4);
    float* sgbias   = (float*)alloc((size_t)NBLK * 1536 * 4);
    __hip_bfloat16* Wbuf = (__hip_bfloat16*)alloc((size_t)8257536 * 2);
    (void)ws_size;

    // weight-buffer offsets (elements), per-block reused
    __hip_bfloat16* ALN1SW  = Wbuf + 0;
    __hip_bfloat16* ALN1SHW = Wbuf + 294912;
    __hip_bfloat16* QKVGT   = Wbuf + 589824;
    __hip_bfloat16* WOT     = Wbuf + 2949120;
    __hip_bfloat16* SGT     = Wbuf + 3538944;
    __hip_bfloat16* ALN2SW  = Wbuf + 4128768;
    __hip_bfloat16* ALN2SHW = Wbuf + 4423680;
    __hip_bfloat16* TW1T    = Wbuf + 4718592;
    __hip_bfloat16* TW2T    = Wbuf + 5898240;
    __hip_bfloat16* TW3T    = Wbuf + 7077888;

    hipMemcpyAsync(A, A_I, (size_t)NTOK * CT * 4, hipMemcpyDeviceToDevice, stream);

    topk_kernel<<<NTOK, 256, 0, stream>>>(X_L, idx);
    ln_kernel<<<NTOK, 256, 0, stream>>>(S_I, LNS, CS);
    snb_kernel<<<8 * NTOK * CS / 256, 256, 0, stream>>>(LNS, aln1_sln_g, aln2_sln_g, snb);
    tobf_kernel<<<NTOK * CS / 256, 256, 0, stream>>>(S_I, S_bf);
    biasprep_kernel<<<NBLK * 3072 / 256, 256, 0, stream>>>(bq, sg_b, tsg_b, qkvgbias, sgbias);

    dim3 gAda(12, 16), gQKVG(48, 16), gSg(24, 16), gOut(12, 16), gTrans(24, 16);

    for (int i = 0; i < NBLK; ++i) {
        // ---- build conversion table for this block's weights ----
        ConvTable tab;
        int p = 0, ts = 0;
        auto add = [&](const float* s, __hip_bfloat16* d, int Kk, int Nn) {
            tab.e[p].src = s; tab.e[p].dst = d; tab.e[p].K = Kk; tab.e[p].N = Nn;
            tab.e[p].tstart = ts; ts += (Kk / 32) * (Nn / 32); ++p;
        };
        add(aln1_sw  + (size_t)i * CS * CT, ALN1SW, 384, 768);
        add(aln1_shw + (size_t)i * CS * CT, ALN1SHW, 384, 768);
        add(Wq + (size_t)i * CT * CT, QKVGT + (size_t)0 * 768 * 768, 768, 768);
        add(Wk + (size_t)i * CT * CT, QKVGT + (size_t)1 * 768 * 768, 768, 768);
        add(Wv + (size_t)i * CT * CT, QKVGT + (size_t)2 * 768 * 768, 768, 768);
        add(Wg + (size_t)i * CT * CT, QKVGT + (size_t)3 * 768 * 768, 768, 768);
        add(Wo + (size_t)i * CT * CT, WOT, 768, 768);
        add(sg_w  + (size_t)i * CS * CT, SGT, 384, 768);
        add(tsg_w + (size_t)i * CS * CT, SGT + (size_t)768 * 384, 384, 768);
        add(aln2_sw  + (size_t)i * CS * CT, ALN2SW, 384, 768);
        add(aln2_shw + (size_t)i * CS * CT, ALN2SHW, 384, 768);
        add(t_w1 + (size_t)i * CT * 2 * CT, TW1T, 768, 1536);
        add(t_w2 + (size_t)i * CT * 2 * CT, TW2T, 768, 1536);
        add(t_w3 + (size_t)i * 2 * CT * CT, TW3T, 1536, 768);
        convT_kernel<<<ts, 256, 0, stream>>>(tab);

        // ---- LocalAttentionPairBias ----
        ln_kernel<<<NTOK, 256, 0, stream>>>(A, LNA, CT);
        gemm_kernel<1><<<gAda, 256, 0, stream>>>(
            snb + (size_t)(2 * i) * NTOK * CS, ALN1SW, ALN1SHW,
            aln1_sb + (size_t)i * CT, LNA, 768, nullptr, an, 384, 768, 768);
        gemm_kernel<0><<<gQKVG, 256, 0, stream>>>(
            an, QKVGT, nullptr, qkvgbias + (size_t)i * 3072, nullptr, 0,
            qkvg, nullptr, 768, 3072, 3072);
        gemm_kernel<0><<<gSg, 256, 0, stream>>>(
            S_bf, SGT, nullptr, sgbias + (size_t)i * 1536, nullptr, 0,
            sg2, nullptr, 384, 1536, 1536);
        pairbias_kernel<<<NTOK * KTOT / 256, 256, 0, stream>>>(
            Z_II, idx, pair_ln_g + (size_t)i * CP, pair_ln_b + (size_t)i * CP,
            Wbp + (size_t)i * CP * NH, biasT);
        attn_kernel<<<NTOK, 256, 0, stream>>>(qkvg, biasT, idx, o2);
        gemm_kernel<3><<<gOut, 256, 0, stream>>>(
            o2, WOT, nullptr, nullptr, sg2, 1536, A, nullptr, 768, 768, 768);

        // ---- ConditionedTransitionBlock ----
        ln_kernel<<<NTOK, 256, 0, stream>>>(A, LNA, CT);
        gemm_kernel<1><<<gAda, 256, 0, stream>>>(
            snb + (size_t)(2 * i + 1) * NTOK * CS, ALN2SW, ALN2SHW,
            aln2_sb + (size_t)i * CT, LNA, 768, nullptr, an, 384, 768, 768);
        gemm_kernel<2><<<gTrans, 256, 0, stream>>>(
            an, TW1T, TW2T, nullptr, nullptr, 0, nullptr, hb, 768, 1536, 1536);
        gemm_kernel<3><<<gOut, 256, 0, stream>>>(
            hb, TW3T, nullptr, nullptr, sg2 + 768, 1536, A, nullptr, 1536, 768, 768);
    }
}

// Round 3
// 535.855 us; speedup vs baseline: 5.3187x; 1.4229x over previous
//
#include <hip/hip_runtime.h>
#include <hip/hip_bf16.h>
#include <math.h>
#include <stdint.h>

#define NTOK 1024
#define CT   768
#define CS   384
#define CP   16
#define NH   16
#define DH   48
#define NBLK 4
#define NL   8
#define NKEY 32
#define KTOT 40
#define SCALE_ 0.14433756729740643f   // 1/sqrt(48)

typedef __attribute__((ext_vector_type(8))) short short8;
typedef __attribute__((ext_vector_type(4))) float f32x4;
typedef __attribute__((ext_vector_type(2))) float f32x2;

#define AS1 __attribute__((address_space(1)))
#define AS3 __attribute__((address_space(3)))

__device__ __forceinline__ float sigmoidf_(float x) {
    return 1.0f / (1.0f + __expf(-x));
}
__device__ __forceinline__ float bf2f(unsigned short u) {
    union { unsigned int i; float f; } v; v.i = (unsigned int)u << 16; return v.f;
}

// async global(16B/lane) -> LDS (wave-uniform base + lane*16)
__device__ __forceinline__ void gl_lds16(const void* g, void* l) {
    __builtin_amdgcn_global_load_lds((const AS1 void*)(uintptr_t)g,
                                     (AS3 void*)(uintptr_t)l, 16, 0, 0);
}

// ---------------------------------------------------------------------------
// Top-k spatial neighbours + local window indices (matches jax.lax.top_k ties)
// ---------------------------------------------------------------------------
__global__ __launch_bounds__(256)
void topk_kernel(const float* __restrict__ X, int* __restrict__ idx) {
    int n = blockIdx.x;
    int t = threadIdx.x;
    __shared__ float d2[NTOK];
    __shared__ float redv[256];
    __shared__ int   redi[256];

    float x0 = X[n * 3 + 0], x1 = X[n * 3 + 1], x2 = X[n * 3 + 2];
    for (int m = t; m < NTOK; m += 256) {
        float dx = x0 - X[m * 3 + 0];
        float dy = x1 - X[m * 3 + 1];
        float dz = x2 - X[m * 3 + 2];
        d2[m] = dx * dx + dy * dy + dz * dz;
    }
    if (t < NL) {
        int loc = n + t - NL / 2;
        loc = loc < 0 ? 0 : (loc > NTOK - 1 ? NTOK - 1 : loc);
        idx[n * KTOT + t] = loc;
    }
    __syncthreads();

    for (int it = 0; it < NKEY; ++it) {
        float bv = INFINITY;
        int bi = NTOK;
        for (int m = t; m < NTOK; m += 256) {
            float v = d2[m];
            if (v < bv) { bv = v; bi = m; }
        }
        redv[t] = bv; redi[t] = bi;
        __syncthreads();
        for (int s = 128; s > 0; s >>= 1) {
            if (t < s) {
                float ov = redv[t + s]; int oi = redi[t + s];
                if (ov < redv[t] || (ov == redv[t] && oi < redi[t])) {
                    redv[t] = ov; redi[t] = oi;
                }
            }
            __syncthreads();
        }
        if (t == 0) {
            idx[n * KTOT + NL + it] = redi[0];
            d2[redi[0]] = INFINITY;
        }
        __syncthreads();
    }
}

// ---------------------------------------------------------------------------
// Row LayerNorm (no affine), fp32 out — used for S_I only
// ---------------------------------------------------------------------------
__global__ __launch_bounds__(256)
void ln_kernel(const float* __restrict__ in, float* __restrict__ out, int C) {
    int row = blockIdx.x;
    int t = threadIdx.x;
    __shared__ float red[256];
    float vals[6];
    int cnt = 0;
    float s = 0.0f;
    for (int c = t; c < C; c += 256) { float v = in[row * C + c]; vals[cnt++] = v; s += v; }
    red[t] = s; __syncthreads();
    for (int st = 128; st > 0; st >>= 1) { if (t < st) red[t] += red[t + st]; __syncthreads(); }
    float mean = red[0] / C;
    __syncthreads();
    float s2 = 0.0f;
    for (int j = 0; j < cnt; ++j) { float d = vals[j] - mean; s2 += d * d; }
    red[t] = s2; __syncthreads();
    for (int st = 128; st > 0; st >>= 1) { if (t < st) red[t] += red[t + st]; __syncthreads(); }
    float rstd = rsqrtf(red[0] / C + 1e-5f);
    for (int j = 0; j < cnt; ++j) {
        int c = t + j * 256;
        out[row * C + c] = (vals[j] - mean) * rstd;
    }
}

// ---------------------------------------------------------------------------
// Per-row LN stats of A [1024][768] -> stats[row] = {mean, rstd}
// ---------------------------------------------------------------------------
__global__ __launch_bounds__(256)
void lnstats_kernel(const float* __restrict__ in, float* __restrict__ stats) {
    int row = blockIdx.x;
    int t = threadIdx.x;
    __shared__ float red[256];
    float v0 = in[row * CT + t];
    float v1 = in[row * CT + t + 256];
    float v2 = in[row * CT + t + 512];
    red[t] = v0 + v1 + v2; __syncthreads();
    for (int st = 128; st > 0; st >>= 1) { if (t < st) red[t] += red[t + st]; __syncthreads(); }
    float mean = red[0] * (1.0f / CT);
    __syncthreads();
    float d0 = v0 - mean, d1 = v1 - mean, d2 = v2 - mean;
    red[t] = d0 * d0 + d1 * d1 + d2 * d2; __syncthreads();
    for (int st = 128; st > 0; st >>= 1) { if (t < st) red[t] += red[t + st]; __syncthreads(); }
    if (t == 0) {
        stats[row * 2] = mean;
        stats[row * 2 + 1] = rsqrtf(red[0] * (1.0f / CT) + 1e-5f);
    }
}

// ---------------------------------------------------------------------------
// Weight convert + transpose: fp32 [K][N] -> bf16 [N][K]
// ---------------------------------------------------------------------------
struct ConvDesc { const float* src; __hip_bfloat16* dst; int K; int N; int tstart; };
struct ConvTable { ConvDesc e[14]; };

__global__ __launch_bounds__(256)
void convT_kernel(ConvTable tab) {
    int b = blockIdx.x;
    int ei = 0;
#pragma unroll
    for (int j = 1; j < 14; ++j) if (b >= tab.e[j].tstart) ei = j;
    ConvDesc d = tab.e[ei];
    int tt = b - d.tstart;
    int ntn = d.N / 32;
    int k0 = (tt / ntn) * 32, n0 = (tt % ntn) * 32;
    __shared__ float s[32][33];
    int tx = threadIdx.x & 31, ty = threadIdx.x >> 5;
#pragma unroll
    for (int i = 0; i < 4; ++i)
        s[ty + 8 * i][tx] = d.src[(size_t)(k0 + ty + 8 * i) * d.N + n0 + tx];
    __syncthreads();
#pragma unroll
    for (int i = 0; i < 4; ++i)
        d.dst[(size_t)(n0 + ty + 8 * i) * d.K + k0 + tx] = __float2bfloat16(s[tx][ty + 8 * i]);
}

// ---------------------------------------------------------------------------
// Small prep kernels
// ---------------------------------------------------------------------------
__global__ __launch_bounds__(256)
void biasprep_kernel(const float* __restrict__ bq, const float* __restrict__ sg_b,
                     const float* __restrict__ tsg_b, float* __restrict__ qb,
                     float* __restrict__ sb2) {
    int t = blockIdx.x * 256 + threadIdx.x;
    if (t < NBLK * 3072) {
        int i = t / 3072, c = t % 3072;
        qb[t] = (c < 768) ? bq[i * 768 + c] : 0.0f;
    }
    if (t < NBLK * 1536) {
        int i = t / 1536, c = t % 1536;
        sb2[t] = (c < 768) ? sg_b[i * 768 + c] : tsg_b[i * 768 + c - 768];
    }
}

__global__ __launch_bounds__(256)
void snb_kernel(const float* __restrict__ LNS, const float* __restrict__ g1,
                const float* __restrict__ g2, __hip_bfloat16* __restrict__ snb) {
    int t = blockIdx.x * 256 + threadIdx.x;
    int j = t / (NTOK * CS);
    int rc = t % (NTOK * CS);
    int c = rc % CS;
    const float* g = ((j & 1) ? g2 : g1) + (j >> 1) * CS;
    snb[t] = __float2bfloat16(LNS[rc] * g[c]);
}

__global__ __launch_bounds__(256)
void tobf_kernel(const float* __restrict__ in, __hip_bfloat16* __restrict__ out) {
    int t = blockIdx.x * 256 + threadIdx.x;
    out[t] = __float2bfloat16(in[t]);
}

// ---------------------------------------------------------------------------
// bf16 MFMA GEMM: tile 64x64, BK=64, 4 waves (2x2), wave does 32x32.
// LDS is XOR-swizzled (16B slot ^ row&7): global source pre-swizzled for
// global_load_lds (linear dest), ds_read applies the same swizzle.
// A: [M][K] bf16. B1/B2: [N][K] bf16 (pre-transposed).
// MODE 0: outf = acc1 + cbias[col]                              (fp32)
// MODE 1: outb = bf16( sigmoid(acc1+cbias)*LN(aux;stats) + acc2 )
// MODE 2: outb = bf16( silu(acc1) * acc2 )
// MODE 3: outf += sigmoid(aux) * acc1
// MODE 4: outb = bf16( acc1 + cbias[col] )
// ---------------------------------------------------------------------------
template <int MODE>
__global__ __launch_bounds__(256)
void gemm_kernel(const __hip_bfloat16* __restrict__ A,
                 const __hip_bfloat16* __restrict__ B1,
                 const __hip_bfloat16* __restrict__ B2,
                 const float* __restrict__ cbias,
                 const float* __restrict__ aux, int ld_aux,
                 const float* __restrict__ stats,
                 float* __restrict__ outf, __hip_bfloat16* __restrict__ outb,
                 int K, int N, int ldo) {
    constexpr bool DUAL = (MODE == 1 || MODE == 2);
    __shared__ __align__(16) char As[8192];
    __shared__ __align__(16) char Bs[8192];
    __shared__ __align__(16) char Bs2[DUAL ? 8192 : 16];

    const int tid = threadIdx.x;
    const int lane = tid & 63;
    const int wid = tid >> 6;
    const int wr = wid >> 1, wc = wid & 1;
    const int row0 = blockIdx.y * 64;
    const int col0 = blockIdx.x * 64;

    // staging: lds slot (row = tid>>3 [+32], s = tid&7) <- global elem (s^(row&7))*8
    const int srow = tid >> 3;
    const int sg_e = (((tid & 7) ^ (srow & 7)) << 3);
    const __hip_bfloat16* ag = A + (size_t)(row0 + srow) * K + sg_e;
    const __hip_bfloat16* bg = B1 + (size_t)(col0 + srow) * K + sg_e;
    const __hip_bfloat16* bg2 = DUAL ? (B2 + (size_t)(col0 + srow) * K + sg_e) : nullptr;
    const size_t r32K = (size_t)32 * K;
    char* alds = As + tid * 16;
    char* blds = Bs + tid * 16;
    char* blds2 = Bs2 + tid * 16;

    f32x4 acc[2][2];
    f32x4 acc2[2][2];
#pragma unroll
    for (int i = 0; i < 2; ++i)
#pragma unroll
        for (int j = 0; j < 2; ++j) {
            acc[i][j] = (f32x4){0.f, 0.f, 0.f, 0.f};
            acc2[i][j] = (f32x4){0.f, 0.f, 0.f, 0.f};
        }

    const int l15 = lane & 15;
    const int lhi = lane >> 4;          // k-chunk 0..3

    for (int k0 = 0; k0 < K; k0 += 64) {
        gl_lds16(ag, alds); gl_lds16(ag + r32K, alds + 4096);
        gl_lds16(bg, blds); gl_lds16(bg + r32K, blds + 4096);
        if (DUAL) { gl_lds16(bg2, blds2); gl_lds16(bg2 + r32K, blds2 + 4096); }
        ag += 64; bg += 64; if (DUAL) bg2 += 64;
        __syncthreads();
#pragma unroll
        for (int kk = 0; kk < 2; ++kk) {
            const int c = lhi + 4 * kk;
            const int ra0 = wr * 32 + l15, ra1 = ra0 + 16;
            const int rb0 = wc * 32 + l15, rb1 = rb0 + 16;
            short8 a0 = *(const short8*)(As + ra0 * 128 + (((c ^ (ra0 & 7)) << 4)));
            short8 a1 = *(const short8*)(As + ra1 * 128 + (((c ^ (ra1 & 7)) << 4)));
            short8 b0 = *(const short8*)(Bs + rb0 * 128 + (((c ^ (rb0 & 7)) << 4)));
            short8 b1 = *(const short8*)(Bs + rb1 * 128 + (((c ^ (rb1 & 7)) << 4)));
            acc[0][0] = __builtin_amdgcn_mfma_f32_16x16x32_bf16(a0, b0, acc[0][0], 0, 0, 0);
            acc[0][1] = __builtin_amdgcn_mfma_f32_16x16x32_bf16(a0, b1, acc[0][1], 0, 0, 0);
            acc[1][0] = __builtin_amdgcn_mfma_f32_16x16x32_bf16(a1, b0, acc[1][0], 0, 0, 0);
            acc[1][1] = __builtin_amdgcn_mfma_f32_16x16x32_bf16(a1, b1, acc[1][1], 0, 0, 0);
            if (DUAL) {
                short8 c0 = *(const short8*)(Bs2 + rb0 * 128 + (((c ^ (rb0 & 7)) << 4)));
                short8 c1 = *(const short8*)(Bs2 + rb1 * 128 + (((c ^ (rb1 & 7)) << 4)));
                acc2[0][0] = __builtin_amdgcn_mfma_f32_16x16x32_bf16(a0, c0, acc2[0][0], 0, 0, 0);
                acc2[0][1] = __builtin_amdgcn_mfma_f32_16x16x32_bf16(a0, c1, acc2[0][1], 0, 0, 0);
                acc2[1][0] = __builtin_amdgcn_mfma_f32_16x16x32_bf16(a1, c0, acc2[1][0], 0, 0, 0);
                acc2[1][1] = __builtin_amdgcn_mfma_f32_16x16x32_bf16(a1, c1, acc2[1][1], 0, 0, 0);
            }
        }
        __syncthreads();
    }

#pragma unroll
    for (int mi = 0; mi < 2; ++mi)
#pragma unroll
        for (int ni = 0; ni < 2; ++ni) {
            f32x4 v1 = acc[mi][ni];
            f32x4 v2 = acc2[mi][ni];
            int col = col0 + wc * 32 + ni * 16 + l15;
            int rbase = row0 + wr * 32 + mi * 16 + lhi * 4;
#pragma unroll
            for (int r = 0; r < 4; ++r) {
                int row = rbase + r;
                size_t o = (size_t)row * ldo + col;
                if (MODE == 0) {
                    outf[o] = v1[r] + (cbias ? cbias[col] : 0.0f);
                } else if (MODE == 1) {
                    float mean = stats[row * 2], rstd = stats[row * 2 + 1];
                    float anv = (aux[(size_t)row * ld_aux + col] - mean) * rstd;
                    float g = sigmoidf_(v1[r] + cbias[col]);
                    outb[o] = __float2bfloat16(g * anv + v2[r]);
                } else if (MODE == 2) {
                    float x = v1[r];
                    outb[o] = __float2bfloat16(x * sigmoidf_(x) * v2[r]);
                } else if (MODE == 3) {
                    outf[o] += sigmoidf_(aux[(size_t)row * ld_aux + col]) * v1[r];
                } else {
                    outb[o] = __float2bfloat16(v1[r] + cbias[col]);
                }
            }
        }
}

// ---------------------------------------------------------------------------
// Pair bias: biasT[n][h][k] = (LN(Z[n, idx[n,k], :]; pg, pb) @ Wb)[h]
// ---------------------------------------------------------------------------
__global__ __launch_bounds__(256)
void pairbias_kernel(const float* __restrict__ Z, const int* __restrict__ idx,
                     const float* __restrict__ pg, const float* __restrict__ pb,
                     const float* __restrict__ Wb, float* __restrict__ biasT) {
    __shared__ float wb[16][16];
    __shared__ float pgs[16], pbs[16];
    int t = threadIdx.x;
    wb[t >> 4][t & 15] = Wb[t];
    if (t < 16) { pgs[t] = pg[t]; pbs[t] = pb[t]; }
    __syncthreads();

    int task = blockIdx.x * 256 + t;
    int n = task / KTOT, k = task % KTOT;
    int m = idx[task];
    const float* z = Z + ((size_t)n * NTOK + m) * CP;
    float v[16];
    float s = 0.0f;
#pragma unroll
    for (int c = 0; c < 16; ++c) { v[c] = z[c]; s += v[c]; }
    float mean = s * (1.0f / 16.0f);
    float s2 = 0.0f;
#pragma unroll
    for (int c = 0; c < 16; ++c) { float d = v[c] - mean; s2 += d * d; }
    float rstd = rsqrtf(s2 * (1.0f / 16.0f) + 1e-5f);
#pragma unroll
    for (int c = 0; c < 16; ++c) v[c] = (v[c] - mean) * rstd * pgs[c] + pbs[c];
#pragma unroll
    for (int h = 0; h < 16; ++h) {
        float a = 0.0f;
#pragma unroll
        for (int c = 0; c < 16; ++c) a += v[c] * wb[c][h];
        biasT[((size_t)n * NH + h) * KTOT + k] = a;
    }
}

// ---------------------------------------------------------------------------
// Attention on bf16 qkvg [1024][3072] (q|k|v|g). One block per token.
// q staged in LDS; vectorized K loads; wave-parallel softmax (16 lanes/head).
// ---------------------------------------------------------------------------
__global__ __launch_bounds__(256)
void attn_kernel(const __hip_bfloat16* __restrict__ qkvg,
                 const float* __restrict__ biasT,
                 const int* __restrict__ idx,
                 __hip_bfloat16* __restrict__ o2) {
    int n = blockIdx.x;
    int t = threadIdx.x;
    __shared__ __align__(16) unsigned short qs[768];
    __shared__ float sc[16][48];
    __shared__ int sidx[KTOT];

    const unsigned short* qg = (const unsigned short*)(qkvg + (size_t)n * 3072);
    if (t < 96) ((short8*)qs)[t] = ((const short8*)qg)[t];
    if (t >= 96 && t < 96 + KTOT) sidx[t - 96] = idx[n * KTOT + (t - 96)];
    __syncthreads();

    // ---- scores ----
    for (int task = t; task < NH * KTOT; task += 256) {
        int h = task / KTOT, k = task - h * KTOT;
        const short8* kp = (const short8*)((const unsigned short*)qkvg +
                                           (size_t)sidx[k] * 3072 + 768 + h * DH);
        const short8* qp = (const short8*)(qs + h * DH);
        float s = 0.0f;
#pragma unroll
        for (int j = 0; j < 6; ++j) {
            short8 kv = kp[j];
            short8 qv = qp[j];
#pragma unroll
            for (int e = 0; e < 8; ++e)
                s += bf2f((unsigned short)qv[e]) * bf2f((unsigned short)kv[e]);
        }
        sc[h][k] = s * SCALE_ + biasT[((size_t)n * NH + h) * KTOT + k];
    }
    __syncthreads();

    // ---- softmax: 16 lanes per head ----
    {
        int h = t >> 4, l = t & 15;
        float v0 = sc[h][l];
        float v1 = sc[h][l + 16];
        float v2 = (l < 8) ? sc[h][l + 32] : -INFINITY;
        float mx = fmaxf(fmaxf(v0, v1), v2);
#pragma unroll
        for (int m = 8; m > 0; m >>= 1) mx = fmaxf(mx, __shfl_xor(mx, m, 16));
        float e0 = __expf(v0 - mx), e1 = __expf(v1 - mx);
        float e2 = (l < 8) ? __expf(v2 - mx) : 0.0f;
        float sm = e0 + e1 + e2;
#pragma unroll
        for (int m = 8; m > 0; m >>= 1) sm += __shfl_xor(sm, m, 16);
        float inv = 1.0f / sm;
        sc[h][l] = e0 * inv;
        sc[h][l + 16] = e1 * inv;
        if (l < 8) sc[h][l + 32] = e2 * inv;
    }
    __syncthreads();

    // ---- PV + gate ----
    for (int task = t; task < CT; task += 256) {
        int h = task / DH, d = task - h * DH;
        const unsigned short* vbase = (const unsigned short*)qkvg + 1536 + h * DH + d;
        float acc = 0.0f;
#pragma unroll
        for (int k = 0; k < KTOT; ++k)
            acc += sc[h][k] * bf2f(vbase[(size_t)sidx[k] * 3072]);
        float g = bf2f(((const unsigned short*)qkvg)[(size_t)n * 3072 + 2304 + task]);
        o2[(size_t)n * CT + task] = __float2bfloat16(sigmoidf_(g) * acc);
    }
}

// ---------------------------------------------------------------------------
// Host orchestration
// ---------------------------------------------------------------------------
extern "C" void kernel_launch(void* const* d_in, const int* in_sizes, int n_in,
                              void* d_out, int out_size, void* d_ws, size_t ws_size,
                              hipStream_t stream) {
    const float* A_I  = (const float*)d_in[0];
    const float* S_I  = (const float*)d_in[1];
    const float* Z_II = (const float*)d_in[2];
    const float* X_L  = (const float*)d_in[3];
    const float* aln1_sln_g = (const float*)d_in[5];
    const float* aln1_sw    = (const float*)d_in[6];
    const float* aln1_sb    = (const float*)d_in[7];
    const float* aln1_shw   = (const float*)d_in[8];
    const float* Wq  = (const float*)d_in[9];
    const float* bq  = (const float*)d_in[10];
    const float* Wk  = (const float*)d_in[11];
    const float* Wv  = (const float*)d_in[12];
    const float* pair_ln_g = (const float*)d_in[13];
    const float* pair_ln_b = (const float*)d_in[14];
    const float* Wbp = (const float*)d_in[15];
    const float* Wg  = (const float*)d_in[16];
    const float* Wo  = (const float*)d_in[17];
    const float* sg_w = (const float*)d_in[18];
    const float* sg_b = (const float*)d_in[19];
    const float* aln2_sln_g = (const float*)d_in[20];
    const float* aln2_sw    = (const float*)d_in[21];
    const float* aln2_sb    = (const float*)d_in[22];
    const float* aln2_shw   = (const float*)d_in[23];
    const float* t_w1 = (const float*)d_in[24];
    const float* t_w2 = (const float*)d_in[25];
    const float* t_w3 = (const float*)d_in[26];
    const float* tsg_w = (const float*)d_in[27];
    const float* tsg_b = (const float*)d_in[28];
    (void)in_sizes; (void)n_in; (void)out_size;

    float* A = (float*)d_out;

    char* ws = (char*)d_ws;
    size_t off = 0;
    auto alloc = [&](size_t bytes) {
        void* p = ws + off;
        off += (bytes + 255) & ~(size_t)255;
        return p;
    };
    int*   idx    = (int*)  alloc(NTOK * KTOT * 4);
    float* LNS    = (float*)alloc((size_t)NTOK * CS * 4);
    float* stats  = (float*)alloc((size_t)NTOK * 2 * 4);
    __hip_bfloat16* S_bf = (__hip_bfloat16*)alloc((size_t)NTOK * CS * 2);
    __hip_bfloat16* snb  = (__hip_bfloat16*)alloc((size_t)8 * NTOK * CS * 2);
    __hip_bfloat16* an   = (__hip_bfloat16*)alloc((size_t)NTOK * CT * 2);
    __hip_bfloat16* qkvg = (__hip_bfloat16*)alloc((size_t)NTOK * 3072 * 2);
    float* sg2    = (float*)alloc((size_t)NTOK * 1536 * 4);
    float* biasT  = (float*)alloc((size_t)NTOK * NH * KTOT * 4);
    __hip_bfloat16* o2 = (__hip_bfloat16*)alloc((size_t)NTOK * CT * 2);
    __hip_bfloat16* hb = (__hip_bfloat16*)alloc((size_t)NTOK * 2 * CT * 2);
    float* qkvgbias = (float*)alloc((size_t)NBLK * 3072 * 4);
    float* sgbias   = (float*)alloc((size_t)NBLK * 1536 * 4);
    __hip_bfloat16* Wbuf = (__hip_bfloat16*)alloc((size_t)8257536 * 2);
    (void)ws_size;

    __hip_bfloat16* ALN1SW  = Wbuf + 0;
    __hip_bfloat16* ALN1SHW = Wbuf + 294912;
    __hip_bfloat16* QKVGT   = Wbuf + 589824;
    __hip_bfloat16* WOT     = Wbuf + 2949120;
    __hip_bfloat16* SGT     = Wbuf + 3538944;
    __hip_bfloat16* ALN2SW  = Wbuf + 4128768;
    __hip_bfloat16* ALN2SHW = Wbuf + 4423680;
    __hip_bfloat16* TW1T    = Wbuf + 4718592;
    __hip_bfloat16* TW2T    = Wbuf + 5898240;
    __hip_bfloat16* TW3T    = Wbuf + 7077888;

    hipMemcpyAsync(A, A_I, (size_t)NTOK * CT * 4, hipMemcpyDeviceToDevice, stream);

    topk_kernel<<<NTOK, 256, 0, stream>>>(X_L, idx);
    ln_kernel<<<NTOK, 256, 0, stream>>>(S_I, LNS, CS);
    snb_kernel<<<8 * NTOK * CS / 256, 256, 0, stream>>>(LNS, aln1_sln_g, aln2_sln_g, snb);
    tobf_kernel<<<NTOK * CS / 256, 256, 0, stream>>>(S_I, S_bf);
    biasprep_kernel<<<NBLK * 3072 / 256, 256, 0, stream>>>(bq, sg_b, tsg_b, qkvgbias, sgbias);

    dim3 gAda(12, 16), gQKVG(48, 16), gSg(24, 16), gOut(12, 16), gTrans(24, 16);

    for (int i = 0; i < NBLK; ++i) {
        ConvTable tab;
        int p = 0, ts = 0;
        auto add = [&](const float* s, __hip_bfloat16* d, int Kk, int Nn) {
            tab.e[p].src = s; tab.e[p].dst = d; tab.e[p].K = Kk; tab.e[p].N = Nn;
            tab.e[p].tstart = ts; ts += (Kk / 32) * (Nn / 32); ++p;
        };
        add(aln1_sw  + (size_t)i * CS * CT, ALN1SW, 384, 768);
        add(aln1_shw + (size_t)i * CS * CT, ALN1SHW, 384, 768);
        add(Wq + (size_t)i * CT * CT, QKVGT + (size_t)0 * 768 * 768, 768, 768);
        add(Wk + (size_t)i * CT * CT, QKVGT + (size_t)1 * 768 * 768, 768, 768);
        add(Wv + (size_t)i * CT * CT, QKVGT + (size_t)2 * 768 * 768, 768, 768);
        add(Wg + (size_t)i * CT * CT, QKVGT + (size_t)3 * 768 * 768, 768, 768);
        add(Wo + (size_t)i * CT * CT, WOT, 768, 768);
        add(sg_w  + (size_t)i * CS * CT, SGT, 384, 768);
        add(tsg_w + (size_t)i * CS * CT, SGT + (size_t)768 * 384, 384, 768);
        add(aln2_sw  + (size_t)i * CS * CT, ALN2SW, 384, 768);
        add(aln2_shw + (size_t)i * CS * CT, ALN2SHW, 384, 768);
        add(t_w1 + (size_t)i * CT * 2 * CT, TW1T, 768, 1536);
        add(t_w2 + (size_t)i * CT * 2 * CT, TW2T, 768, 1536);
        add(t_w3 + (size_t)i * 2 * CT * CT, TW3T, 1536, 768);
        convT_kernel<<<ts, 256, 0, stream>>>(tab);

        // ---- LocalAttentionPairBias ----
        lnstats_kernel<<<NTOK, 256, 0, stream>>>(A, stats);
        gemm_kernel<1><<<gAda, 256, 0, stream>>>(
            snb + (size_t)(2 * i) * NTOK * CS, ALN1SW, ALN1SHW,
            aln1_sb + (size_t)i * CT, A, 768, stats, nullptr, an, 384, 768, 768);
        gemm_kernel<4><<<gQKVG, 256, 0, stream>>>(
            an, QKVGT, nullptr, qkvgbias + (size_t)i * 3072, nullptr, 0, nullptr,
            nullptr, qkvg, 768, 3072, 3072);
        gemm_kernel<0><<<gSg, 256, 0, stream>>>(
            S_bf, SGT, nullptr, sgbias + (size_t)i * 1536, nullptr, 0, nullptr,
            sg2, nullptr, 384, 1536, 1536);
        pairbias_kernel<<<NTOK * KTOT / 256, 256, 0, stream>>>(
            Z_II, idx, pair_ln_g + (size_t)i * CP, pair_ln_b + (size_t)i * CP,
            Wbp + (size_t)i * CP * NH, biasT);
        attn_kernel<<<NTOK, 256, 0, stream>>>(qkvg, biasT, idx, o2);
        gemm_kernel<3><<<gOut, 256, 0, stream>>>(
            o2, WOT, nullptr, nullptr, sg2, 1536, nullptr, A, nullptr, 768, 768, 768);

        // ---- ConditionedTransitionBlock ----
        lnstats_kernel<<<NTOK, 256, 0, stream>>>(A, stats);
        gemm_kernel<1><<<gAda, 256, 0, stream>>>(
            snb + (size_t)(2 * i + 1) * NTOK * CS, ALN2SW, ALN2SHW,
            aln2_sb + (size_t)i * CT, A, 768, stats, nullptr, an, 384, 768, 768);
        gemm_kernel<2><<<gTrans, 256, 0, stream>>>(
            an, TW1T, TW2T, nullptr, nullptr, 0, nullptr, nullptr, hb, 768, 1536, 1536);
        gemm_kernel<3><<<gOut, 256, 0, stream>>>(
            hb, TW3T, nullptr, nullptr, sg2 + 768, 1536, nullptr, A, nullptr, 1536, 768, 768);
    }
}

// Round 4
// 520.698 us; speedup vs baseline: 5.4735x; 1.0291x over previous
//
#include <hip/hip_runtime.h>
#include <hip/hip_bf16.h>
#include <math.h>
#include <stdint.h>

#define NTOK 1024
#define CT   768
#define CS   384
#define CP   16
#define NH   16
#define DH   48
#define NBLK 4
#define NL   8
#define NKEY 32
#define KTOT 40
#define SCALE_ 0.14433756729740643f   // 1/sqrt(48)

typedef __attribute__((ext_vector_type(8))) short short8;
typedef __attribute__((ext_vector_type(4))) float f32x4;

#define AS1 __attribute__((address_space(1)))
#define AS3 __attribute__((address_space(3)))

__device__ __forceinline__ float sigmoidf_(float x) {
    return 1.0f / (1.0f + __expf(-x));
}
__device__ __forceinline__ float bf2f(unsigned short u) {
    union { unsigned int i; float f; } v; v.i = (unsigned int)u << 16; return v.f;
}

// async global(16B/lane) -> LDS (wave-uniform base + lane*16)
__device__ __forceinline__ void gl_lds16(const void* g, void* l) {
    __builtin_amdgcn_global_load_lds((const AS1 void*)(uintptr_t)g,
                                     (AS3 void*)(uintptr_t)l, 16, 0, 0);
}

// ---------------------------------------------------------------------------
// Top-k spatial neighbours: one WAVE per token, barrier-free shuffle argmin.
// Key = (f32bits(d2)<<32)|m : min key == min distance, tie -> lowest index.
// Set-equality with jax.lax.top_k suffices (attention is permutation-
// invariant over the gathered key set).
// ---------------------------------------------------------------------------
__global__ __launch_bounds__(256)
void topk_kernel(const float* __restrict__ X, int* __restrict__ idx) {
    const int w = threadIdx.x >> 6;
    const int l = threadIdx.x & 63;
    const int n = blockIdx.x * 4 + w;

    const float x0 = X[n * 3 + 0], x1 = X[n * 3 + 1], x2 = X[n * 3 + 2];
    float d[16];
    unsigned long long lkey = ~0ull;
#pragma unroll
    for (int j = 0; j < 16; ++j) {
        int m = j * 64 + l;
        float dx = x0 - X[m * 3 + 0];
        float dy = x1 - X[m * 3 + 1];
        float dz = x2 - X[m * 3 + 2];
        float v = dx * dx + dy * dy + dz * dz;
        d[j] = v;
        unsigned long long key =
            ((unsigned long long)__float_as_uint(v) << 32) | (unsigned int)m;
        lkey = key < lkey ? key : lkey;
    }
    if (l < NL) {
        int loc = n + l - NL / 2;
        loc = loc < 0 ? 0 : (loc > NTOK - 1 ? NTOK - 1 : loc);
        idx[n * KTOT + l] = loc;
    }

    for (int it = 0; it < NKEY; ++it) {
        unsigned long long rk = lkey;
#pragma unroll
        for (int s = 32; s > 0; s >>= 1) {
            unsigned long long o = __shfl_xor(rk, s, 64);
            rk = o < rk ? o : rk;
        }
        unsigned int win = (unsigned int)rk;
        if (l == 0) idx[n * KTOT + NL + it] = (int)win;
        if ((int)(win & 63) == l) {
            int jw = (int)(win >> 6);
            unsigned long long nk = ~0ull;
#pragma unroll
            for (int j = 0; j < 16; ++j) {
                if (j == jw) d[j] = INFINITY;
                unsigned long long key =
                    ((unsigned long long)__float_as_uint(d[j]) << 32) |
                    (unsigned int)(j * 64 + l);
                nk = key < nk ? key : nk;
            }
            lkey = nk;
        }
    }
}

// ---------------------------------------------------------------------------
// Row LayerNorm (no affine), fp32 out — used for S_I only
// ---------------------------------------------------------------------------
__global__ __launch_bounds__(256)
void ln_kernel(const float* __restrict__ in, float* __restrict__ out, int C) {
    int row = blockIdx.x;
    int t = threadIdx.x;
    __shared__ float red[256];
    float vals[6];
    int cnt = 0;
    float s = 0.0f;
    for (int c = t; c < C; c += 256) { float v = in[row * C + c]; vals[cnt++] = v; s += v; }
    red[t] = s; __syncthreads();
    for (int st = 128; st > 0; st >>= 1) { if (t < st) red[t] += red[t + st]; __syncthreads(); }
    float mean = red[0] / C;
    __syncthreads();
    float s2 = 0.0f;
    for (int j = 0; j < cnt; ++j) { float d = vals[j] - mean; s2 += d * d; }
    red[t] = s2; __syncthreads();
    for (int st = 128; st > 0; st >>= 1) { if (t < st) red[t] += red[t + st]; __syncthreads(); }
    float rstd = rsqrtf(red[0] / C + 1e-5f);
    for (int j = 0; j < cnt; ++j) {
        int c = t + j * 256;
        out[row * C + c] = (vals[j] - mean) * rstd;
    }
}

// ---------------------------------------------------------------------------
// Per-row LN stats of A [1024][768] -> stats[row] = {mean, rstd}
// ---------------------------------------------------------------------------
__global__ __launch_bounds__(256)
void lnstats_kernel(const float* __restrict__ in, float* __restrict__ stats) {
    int row = blockIdx.x;
    int t = threadIdx.x;
    __shared__ float red[256];
    float v0 = in[row * CT + t];
    float v1 = in[row * CT + t + 256];
    float v2 = in[row * CT + t + 512];
    red[t] = v0 + v1 + v2; __syncthreads();
    for (int st = 128; st > 0; st >>= 1) { if (t < st) red[t] += red[t + st]; __syncthreads(); }
    float mean = red[0] * (1.0f / CT);
    __syncthreads();
    float d0 = v0 - mean, d1 = v1 - mean, d2 = v2 - mean;
    red[t] = d0 * d0 + d1 * d1 + d2 * d2; __syncthreads();
    for (int st = 128; st > 0; st >>= 1) { if (t < st) red[t] += red[t + st]; __syncthreads(); }
    if (t == 0) {
        stats[row * 2] = mean;
        stats[row * 2 + 1] = rsqrtf(red[0] * (1.0f / CT) + 1e-5f);
    }
}

// ---------------------------------------------------------------------------
// Weight convert + transpose: fp32 [K][N] -> bf16 [N][K]
// ---------------------------------------------------------------------------
struct ConvDesc { const float* src; __hip_bfloat16* dst; int K; int N; int tstart; };
struct ConvTable { ConvDesc e[14]; };

__global__ __launch_bounds__(256)
void convT_kernel(ConvTable tab) {
    int b = blockIdx.x;
    int ei = 0;
#pragma unroll
    for (int j = 1; j < 14; ++j) if (b >= tab.e[j].tstart) ei = j;
    ConvDesc d = tab.e[ei];
    int tt = b - d.tstart;
    int ntn = d.N / 32;
    int k0 = (tt / ntn) * 32, n0 = (tt % ntn) * 32;
    __shared__ float s[32][33];
    int tx = threadIdx.x & 31, ty = threadIdx.x >> 5;
#pragma unroll
    for (int i = 0; i < 4; ++i)
        s[ty + 8 * i][tx] = d.src[(size_t)(k0 + ty + 8 * i) * d.N + n0 + tx];
    __syncthreads();
#pragma unroll
    for (int i = 0; i < 4; ++i)
        d.dst[(size_t)(n0 + ty + 8 * i) * d.K + k0 + tx] = __float2bfloat16(s[tx][ty + 8 * i]);
}

// ---------------------------------------------------------------------------
// Small prep kernels
// ---------------------------------------------------------------------------
__global__ __launch_bounds__(256)
void biasprep_kernel(const float* __restrict__ bq, const float* __restrict__ sg_b,
                     const float* __restrict__ tsg_b, float* __restrict__ qb,
                     float* __restrict__ sb2) {
    int t = blockIdx.x * 256 + threadIdx.x;
    if (t < NBLK * 3072) {
        int i = t / 3072, c = t % 3072;
        qb[t] = (c < 768) ? bq[i * 768 + c] : 0.0f;
    }
    if (t < NBLK * 1536) {
        int i = t / 1536, c = t % 1536;
        sb2[t] = (c < 768) ? sg_b[i * 768 + c] : tsg_b[i * 768 + c - 768];
    }
}

__global__ __launch_bounds__(256)
void snb_kernel(const float* __restrict__ LNS, const float* __restrict__ g1,
                const float* __restrict__ g2, __hip_bfloat16* __restrict__ snb) {
    int t = blockIdx.x * 256 + threadIdx.x;
    int j = t / (NTOK * CS);
    int rc = t % (NTOK * CS);
    int c = rc % CS;
    const float* g = ((j & 1) ? g2 : g1) + (j >> 1) * CS;
    snb[t] = __float2bfloat16(LNS[rc] * g[c]);
}

__global__ __launch_bounds__(256)
void tobf_kernel(const float* __restrict__ in, __hip_bfloat16* __restrict__ out) {
    int t = blockIdx.x * 256 + threadIdx.x;
    out[t] = __float2bfloat16(in[t]);
}

// ---------------------------------------------------------------------------
// bf16 MFMA GEMM: tile 64x64, BK=64, 4 waves (2x2), wave does 32x32.
// LDS XOR-swizzled: pre-swizzled global source for global_load_lds (linear
// dest) + swizzled ds_read (rule #21-correct).
// MODE 0: outf = acc1 + cbias[col]                              (fp32)
// MODE 1: outb = bf16( sigmoid(acc1+cbias)*LN(aux;stats) + acc2 )
// MODE 2: outb = bf16( silu(acc1) * acc2 )
// MODE 3: outf += sigmoid(aux) * acc1
// MODE 4: outb = bf16( acc1 + cbias[col] )
// ---------------------------------------------------------------------------
template <int MODE>
__global__ __launch_bounds__(256)
void gemm_kernel(const __hip_bfloat16* __restrict__ A,
                 const __hip_bfloat16* __restrict__ B1,
                 const __hip_bfloat16* __restrict__ B2,
                 const float* __restrict__ cbias,
                 const float* __restrict__ aux, int ld_aux,
                 const float* __restrict__ stats,
                 float* __restrict__ outf, __hip_bfloat16* __restrict__ outb,
                 int K, int N, int ldo) {
    constexpr bool DUAL = (MODE == 1 || MODE == 2);
    __shared__ __align__(16) char As[8192];
    __shared__ __align__(16) char Bs[8192];
    __shared__ __align__(16) char Bs2[DUAL ? 8192 : 16];

    const int tid = threadIdx.x;
    const int lane = tid & 63;
    const int wid = tid >> 6;
    const int wr = wid >> 1, wc = wid & 1;
    const int row0 = blockIdx.y * 64;
    const int col0 = blockIdx.x * 64;

    const int srow = tid >> 3;
    const int sg_e = (((tid & 7) ^ (srow & 7)) << 3);
    const __hip_bfloat16* ag = A + (size_t)(row0 + srow) * K + sg_e;
    const __hip_bfloat16* bg = B1 + (size_t)(col0 + srow) * K + sg_e;
    const __hip_bfloat16* bg2 = DUAL ? (B2 + (size_t)(col0 + srow) * K + sg_e) : nullptr;
    const size_t r32K = (size_t)32 * K;
    char* alds = As + tid * 16;
    char* blds = Bs + tid * 16;
    char* blds2 = Bs2 + tid * 16;

    f32x4 acc[2][2];
    f32x4 acc2[2][2];
#pragma unroll
    for (int i = 0; i < 2; ++i)
#pragma unroll
        for (int j = 0; j < 2; ++j) {
            acc[i][j] = (f32x4){0.f, 0.f, 0.f, 0.f};
            acc2[i][j] = (f32x4){0.f, 0.f, 0.f, 0.f};
        }

    const int l15 = lane & 15;
    const int lhi = lane >> 4;

    for (int k0 = 0; k0 < K; k0 += 64) {
        gl_lds16(ag, alds); gl_lds16(ag + r32K, alds + 4096);
        gl_lds16(bg, blds); gl_lds16(bg + r32K, blds + 4096);
        if (DUAL) { gl_lds16(bg2, blds2); gl_lds16(bg2 + r32K, blds2 + 4096); }
        ag += 64; bg += 64; if (DUAL) bg2 += 64;
        __syncthreads();
#pragma unroll
        for (int kk = 0; kk < 2; ++kk) {
            const int c = lhi + 4 * kk;
            const int ra0 = wr * 32 + l15, ra1 = ra0 + 16;
            const int rb0 = wc * 32 + l15, rb1 = rb0 + 16;
            short8 a0 = *(const short8*)(As + ra0 * 128 + (((c ^ (ra0 & 7)) << 4)));
            short8 a1 = *(const short8*)(As + ra1 * 128 + (((c ^ (ra1 & 7)) << 4)));
            short8 b0 = *(const short8*)(Bs + rb0 * 128 + (((c ^ (rb0 & 7)) << 4)));
            short8 b1 = *(const short8*)(Bs + rb1 * 128 + (((c ^ (rb1 & 7)) << 4)));
            acc[0][0] = __builtin_amdgcn_mfma_f32_16x16x32_bf16(a0, b0, acc[0][0], 0, 0, 0);
            acc[0][1] = __builtin_amdgcn_mfma_f32_16x16x32_bf16(a0, b1, acc[0][1], 0, 0, 0);
            acc[1][0] = __builtin_amdgcn_mfma_f32_16x16x32_bf16(a1, b0, acc[1][0], 0, 0, 0);
            acc[1][1] = __builtin_amdgcn_mfma_f32_16x16x32_bf16(a1, b1, acc[1][1], 0, 0, 0);
            if (DUAL) {
                short8 c0 = *(const short8*)(Bs2 + rb0 * 128 + (((c ^ (rb0 & 7)) << 4)));
                short8 c1 = *(const short8*)(Bs2 + rb1 * 128 + (((c ^ (rb1 & 7)) << 4)));
                acc2[0][0] = __builtin_amdgcn_mfma_f32_16x16x32_bf16(a0, c0, acc2[0][0], 0, 0, 0);
                acc2[0][1] = __builtin_amdgcn_mfma_f32_16x16x32_bf16(a0, c1, acc2[0][1], 0, 0, 0);
                acc2[1][0] = __builtin_amdgcn_mfma_f32_16x16x32_bf16(a1, c0, acc2[1][0], 0, 0, 0);
                acc2[1][1] = __builtin_amdgcn_mfma_f32_16x16x32_bf16(a1, c1, acc2[1][1], 0, 0, 0);
            }
        }
        __syncthreads();
    }

#pragma unroll
    for (int mi = 0; mi < 2; ++mi)
#pragma unroll
        for (int ni = 0; ni < 2; ++ni) {
            f32x4 v1 = acc[mi][ni];
            f32x4 v2 = acc2[mi][ni];
            int col = col0 + wc * 32 + ni * 16 + l15;
            int rbase = row0 + wr * 32 + mi * 16 + lhi * 4;
#pragma unroll
            for (int r = 0; r < 4; ++r) {
                int row = rbase + r;
                size_t o = (size_t)row * ldo + col;
                if (MODE == 0) {
                    outf[o] = v1[r] + (cbias ? cbias[col] : 0.0f);
                } else if (MODE == 1) {
                    float mean = stats[row * 2], rstd = stats[row * 2 + 1];
                    float anv = (aux[(size_t)row * ld_aux + col] - mean) * rstd;
                    float g = sigmoidf_(v1[r] + cbias[col]);
                    outb[o] = __float2bfloat16(g * anv + v2[r]);
                } else if (MODE == 2) {
                    float x = v1[r];
                    outb[o] = __float2bfloat16(x * sigmoidf_(x) * v2[r]);
                } else if (MODE == 3) {
                    outf[o] += sigmoidf_(aux[(size_t)row * ld_aux + col]) * v1[r];
                } else {
                    outb[o] = __float2bfloat16(v1[r] + cbias[col]);
                }
            }
        }
}

// ---------------------------------------------------------------------------
// Attention + fused pair bias. One block per token. bf16 qkvg [1024][3072].
// Phase 0: stage q, idx, Wb, pg/pb.  Phase 1: LN(z) rows (t<40).
// Phase 2: scores (QK + bias dot).   Phase 3: wave-parallel softmax.
// Phase 4: vectorized PV + gate (16B loads/stores).
// ---------------------------------------------------------------------------
__global__ __launch_bounds__(256)
void attn_kernel(const __hip_bfloat16* __restrict__ qkvg,
                 const float* __restrict__ Z,
                 const int* __restrict__ idx,
                 const float* __restrict__ pg, const float* __restrict__ pb,
                 const float* __restrict__ Wbp,
                 __hip_bfloat16* __restrict__ o2) {
    int n = blockIdx.x;
    int t = threadIdx.x;
    __shared__ __align__(16) unsigned short qs[768];
    __shared__ float sc[16][48];
    __shared__ float lnz[KTOT][16];
    __shared__ float wb[16][17];
    __shared__ float pgs[16], pbs[16];
    __shared__ int sidx[KTOT];

    wb[t >> 4][t & 15] = Wbp[t];
    if (t < 96) ((short8*)qs)[t] = ((const short8*)(qkvg + (size_t)n * 3072))[t];
    if (t >= 96 && t < 96 + KTOT) sidx[t - 96] = idx[n * KTOT + (t - 96)];
    if (t >= 160 && t < 176) pgs[t - 160] = pg[t - 160];
    if (t >= 176 && t < 192) pbs[t - 176] = pb[t - 176];
    __syncthreads();

    // ---- LN of gathered pair rows ----
    if (t < KTOT) {
        const f32x4* z = (const f32x4*)(Z + ((size_t)n * NTOK + sidx[t]) * CP);
        f32x4 z0 = z[0], z1 = z[1], z2 = z[2], z3 = z[3];
        float v[16];
#pragma unroll
        for (int e = 0; e < 4; ++e) { v[e] = z0[e]; v[4 + e] = z1[e]; v[8 + e] = z2[e]; v[12 + e] = z3[e]; }
        float s = 0.0f;
#pragma unroll
        for (int c = 0; c < 16; ++c) s += v[c];
        float mean = s * (1.0f / 16.0f);
        float s2 = 0.0f;
#pragma unroll
        for (int c = 0; c < 16; ++c) { float d = v[c] - mean; s2 += d * d; }
        float rstd = rsqrtf(s2 * (1.0f / 16.0f) + 1e-5f);
#pragma unroll
        for (int c = 0; c < 16; ++c) lnz[t][c] = (v[c] - mean) * rstd * pgs[c] + pbs[c];
    }
    __syncthreads();

    // ---- scores: QK^T * scale + bias ----
    for (int task = t; task < NH * KTOT; task += 256) {
        int h = task / KTOT, k = task - h * KTOT;
        const short8* kp = (const short8*)((const unsigned short*)qkvg +
                                           (size_t)sidx[k] * 3072 + 768 + h * DH);
        const short8* qp = (const short8*)(qs + h * DH);
        float s = 0.0f;
#pragma unroll
        for (int j = 0; j < 6; ++j) {
            short8 kv = kp[j];
            short8 qv = qp[j];
#pragma unroll
            for (int e = 0; e < 8; ++e)
                s += bf2f((unsigned short)qv[e]) * bf2f((unsigned short)kv[e]);
        }
        float bias = 0.0f;
#pragma unroll
        for (int c = 0; c < 16; ++c) bias += lnz[k][c] * wb[c][h];
        sc[h][k] = s * SCALE_ + bias;
    }
    __syncthreads();

    // ---- softmax: 16 lanes per head ----
    {
        int h = t >> 4, l = t & 15;
        float v0 = sc[h][l];
        float v1 = sc[h][l + 16];
        float v2 = (l < 8) ? sc[h][l + 32] : -INFINITY;
        float mx = fmaxf(fmaxf(v0, v1), v2);
#pragma unroll
        for (int m = 8; m > 0; m >>= 1) mx = fmaxf(mx, __shfl_xor(mx, m, 16));
        float e0 = __expf(v0 - mx), e1 = __expf(v1 - mx);
        float e2 = (l < 8) ? __expf(v2 - mx) : 0.0f;
        float sm = e0 + e1 + e2;
#pragma unroll
        for (int m = 8; m > 0; m >>= 1) sm += __shfl_xor(sm, m, 16);
        float inv = 1.0f / sm;
        sc[h][l] = e0 * inv;
        sc[h][l + 16] = e1 * inv;
        if (l < 8) sc[h][l + 32] = e2 * inv;
    }
    __syncthreads();

    // ---- PV + gate, vectorized 8 dims/thread ----
    if (t < 96) {
        int h = t / 6, c6 = t - h * 6;
        int d0 = c6 * 8;
        const unsigned short* vbase = (const unsigned short*)qkvg + 1536 + h * DH + d0;
        float acc[8] = {0, 0, 0, 0, 0, 0, 0, 0};
        for (int k = 0; k < KTOT; ++k) {
            short8 vv = *(const short8*)(vbase + (size_t)sidx[k] * 3072);
            float w = sc[h][k];
#pragma unroll
            for (int e = 0; e < 8; ++e) acc[e] += w * bf2f((unsigned short)vv[e]);
        }
        short8 gv = *(const short8*)((const unsigned short*)qkvg +
                                     (size_t)n * 3072 + 2304 + h * DH + d0);
        short8 ov;
#pragma unroll
        for (int e = 0; e < 8; ++e) {
            float g = sigmoidf_(bf2f((unsigned short)gv[e]));
            ov[e] = (short)__bfloat16_as_ushort(__float2bfloat16(g * acc[e]));
        }
        *(short8*)((unsigned short*)o2 + (size_t)n * CT + h * DH + d0) = ov;
    }
}

// ---------------------------------------------------------------------------
// Host orchestration
// ---------------------------------------------------------------------------
extern "C" void kernel_launch(void* const* d_in, const int* in_sizes, int n_in,
                              void* d_out, int out_size, void* d_ws, size_t ws_size,
                              hipStream_t stream) {
    const float* A_I  = (const float*)d_in[0];
    const float* S_I  = (const float*)d_in[1];
    const float* Z_II = (const float*)d_in[2];
    const float* X_L  = (const float*)d_in[3];
    const float* aln1_sln_g = (const float*)d_in[5];
    const float* aln1_sw    = (const float*)d_in[6];
    const float* aln1_sb    = (const float*)d_in[7];
    const float* aln1_shw   = (const float*)d_in[8];
    const float* Wq  = (const float*)d_in[9];
    const float* bq  = (const float*)d_in[10];
    const float* Wk  = (const float*)d_in[11];
    const float* Wv  = (const float*)d_in[12];
    const float* pair_ln_g = (const float*)d_in[13];
    const float* pair_ln_b = (const float*)d_in[14];
    const float* Wbp = (const float*)d_in[15];
    const float* Wg  = (const float*)d_in[16];
    const float* Wo  = (const float*)d_in[17];
    const float* sg_w = (const float*)d_in[18];
    const float* sg_b = (const float*)d_in[19];
    const float* aln2_sln_g = (const float*)d_in[20];
    const float* aln2_sw    = (const float*)d_in[21];
    const float* aln2_sb    = (const float*)d_in[22];
    const float* aln2_shw   = (const float*)d_in[23];
    const float* t_w1 = (const float*)d_in[24];
    const float* t_w2 = (const float*)d_in[25];
    const float* t_w3 = (const float*)d_in[26];
    const float* tsg_w = (const float*)d_in[27];
    const float* tsg_b = (const float*)d_in[28];
    (void)in_sizes; (void)n_in; (void)out_size;

    float* A = (float*)d_out;

    char* ws = (char*)d_ws;
    size_t off = 0;
    auto alloc = [&](size_t bytes) {
        void* p = ws + off;
        off += (bytes + 255) & ~(size_t)255;
        return p;
    };
    int*   idx    = (int*)  alloc(NTOK * KTOT * 4);
    float* LNS    = (float*)alloc((size_t)NTOK * CS * 4);
    float* stats  = (float*)alloc((size_t)NTOK * 2 * 4);
    __hip_bfloat16* S_bf = (__hip_bfloat16*)alloc((size_t)NTOK * CS * 2);
    __hip_bfloat16* snb  = (__hip_bfloat16*)alloc((size_t)8 * NTOK * CS * 2);
    __hip_bfloat16* an   = (__hip_bfloat16*)alloc((size_t)NTOK * CT * 2);
    __hip_bfloat16* qkvg = (__hip_bfloat16*)alloc((size_t)NTOK * 3072 * 2);
    float* sg2    = (float*)alloc((size_t)NTOK * 1536 * 4);
    __hip_bfloat16* o2 = (__hip_bfloat16*)alloc((size_t)NTOK * CT * 2);
    __hip_bfloat16* hb = (__hip_bfloat16*)alloc((size_t)NTOK * 2 * CT * 2);
    float* qkvgbias = (float*)alloc((size_t)NBLK * 3072 * 4);
    float* sgbias   = (float*)alloc((size_t)NBLK * 1536 * 4);
    __hip_bfloat16* Wbuf = (__hip_bfloat16*)alloc((size_t)8257536 * 2);
    (void)ws_size;

    __hip_bfloat16* ALN1SW  = Wbuf + 0;
    __hip_bfloat16* ALN1SHW = Wbuf + 294912;
    __hip_bfloat16* QKVGT   = Wbuf + 589824;
    __hip_bfloat16* WOT     = Wbuf + 2949120;
    __hip_bfloat16* SGT     = Wbuf + 3538944;
    __hip_bfloat16* ALN2SW  = Wbuf + 4128768;
    __hip_bfloat16* ALN2SHW = Wbuf + 4423680;
    __hip_bfloat16* TW1T    = Wbuf + 4718592;
    __hip_bfloat16* TW2T    = Wbuf + 5898240;
    __hip_bfloat16* TW3T    = Wbuf + 7077888;

    hipMemcpyAsync(A, A_I, (size_t)NTOK * CT * 4, hipMemcpyDeviceToDevice, stream);

    topk_kernel<<<NTOK / 4, 256, 0, stream>>>(X_L, idx);
    ln_kernel<<<NTOK, 256, 0, stream>>>(S_I, LNS, CS);
    snb_kernel<<<8 * NTOK * CS / 256, 256, 0, stream>>>(LNS, aln1_sln_g, aln2_sln_g, snb);
    tobf_kernel<<<NTOK * CS / 256, 256, 0, stream>>>(S_I, S_bf);
    biasprep_kernel<<<NBLK * 3072 / 256, 256, 0, stream>>>(bq, sg_b, tsg_b, qkvgbias, sgbias);

    dim3 gAda(12, 16), gQKVG(48, 16), gSg(24, 16), gOut(12, 16), gTrans(24, 16);

    for (int i = 0; i < NBLK; ++i) {
        ConvTable tab;
        int p = 0, ts = 0;
        auto add = [&](const float* s, __hip_bfloat16* d, int Kk, int Nn) {
            tab.e[p].src = s; tab.e[p].dst = d; tab.e[p].K = Kk; tab.e[p].N = Nn;
            tab.e[p].tstart = ts; ts += (Kk / 32) * (Nn / 32); ++p;
        };
        add(aln1_sw  + (size_t)i * CS * CT, ALN1SW, 384, 768);
        add(aln1_shw + (size_t)i * CS * CT, ALN1SHW, 384, 768);
        add(Wq + (size_t)i * CT * CT, QKVGT + (size_t)0 * 768 * 768, 768, 768);
        add(Wk + (size_t)i * CT * CT, QKVGT + (size_t)1 * 768 * 768, 768, 768);
        add(Wv + (size_t)i * CT * CT, QKVGT + (size_t)2 * 768 * 768, 768, 768);
        add(Wg + (size_t)i * CT * CT, QKVGT + (size_t)3 * 768 * 768, 768, 768);
        add(Wo + (size_t)i * CT * CT, WOT, 768, 768);
        add(sg_w  + (size_t)i * CS * CT, SGT, 384, 768);
        add(tsg_w + (size_t)i * CS * CT, SGT + (size_t)768 * 384, 384, 768);
        add(aln2_sw  + (size_t)i * CS * CT, ALN2SW, 384, 768);
        add(aln2_shw + (size_t)i * CS * CT, ALN2SHW, 384, 768);
        add(t_w1 + (size_t)i * CT * 2 * CT, TW1T, 768, 1536);
        add(t_w2 + (size_t)i * CT * 2 * CT, TW2T, 768, 1536);
        add(t_w3 + (size_t)i * 2 * CT * CT, TW3T, 1536, 768);
        convT_kernel<<<ts, 256, 0, stream>>>(tab);

        // ---- LocalAttentionPairBias ----
        lnstats_kernel<<<NTOK, 256, 0, stream>>>(A, stats);
        gemm_kernel<1><<<gAda, 256, 0, stream>>>(
            snb + (size_t)(2 * i) * NTOK * CS, ALN1SW, ALN1SHW,
            aln1_sb + (size_t)i * CT, A, 768, stats, nullptr, an, 384, 768, 768);
        gemm_kernel<4><<<gQKVG, 256, 0, stream>>>(
            an, QKVGT, nullptr, qkvgbias + (size_t)i * 3072, nullptr, 0, nullptr,
            nullptr, qkvg, 768, 3072, 3072);
        gemm_kernel<0><<<gSg, 256, 0, stream>>>(
            S_bf, SGT, nullptr, sgbias + (size_t)i * 1536, nullptr, 0, nullptr,
            sg2, nullptr, 384, 1536, 1536);
        attn_kernel<<<NTOK, 256, 0, stream>>>(
            qkvg, Z_II, idx, pair_ln_g + (size_t)i * CP, pair_ln_b + (size_t)i * CP,
            Wbp + (size_t)i * CP * NH, o2);
        gemm_kernel<3><<<gOut, 256, 0, stream>>>(
            o2, WOT, nullptr, nullptr, sg2, 1536, nullptr, A, nullptr, 768, 768, 768);

        // ---- ConditionedTransitionBlock ----
        lnstats_kernel<<<NTOK, 256, 0, stream>>>(A, stats);
        gemm_kernel<1><<<gAda, 256, 0, stream>>>(
            snb + (size_t)(2 * i + 1) * NTOK * CS, ALN2SW, ALN2SHW,
            aln2_sb + (size_t)i * CT, A, 768, stats, nullptr, an, 384, 768, 768);
        gemm_kernel<2><<<gTrans, 256, 0, stream>>>(
            an, TW1T, TW2T, nullptr, nullptr, 0, nullptr, nullptr, hb, 768, 1536, 1536);
        gemm_kernel<3><<<gOut, 256, 0, stream>>>(
            hb, TW3T, nullptr, nullptr, sg2 + 768, 1536, nullptr, A, nullptr, 1536, 768, 768);
    }
}

// Round 5
// 518.649 us; speedup vs baseline: 5.4951x; 1.0040x over previous
//
#include <hip/hip_runtime.h>
#include <hip/hip_bf16.h>
#include <math.h>
#include <stdint.h>

#define NTOK 1024
#define CT   768
#define CS   384
#define CP   16
#define NH   16
#define DH   48
#define NBLK 4
#define NL   8
#define NKEY 32
#define KTOT 40
#define SCALE_ 0.14433756729740643f   // 1/sqrt(48)

typedef __attribute__((ext_vector_type(8))) short short8;
typedef __attribute__((ext_vector_type(4))) float f32x4;

#define AS1 __attribute__((address_space(1)))
#define AS3 __attribute__((address_space(3)))

__device__ __forceinline__ float sigmoidf_(float x) {
    return 1.0f / (1.0f + __expf(-x));
}
__device__ __forceinline__ float bf2f(unsigned short u) {
    union { unsigned int i; float f; } v; v.i = (unsigned int)u << 16; return v.f;
}

// async global(16B/lane) -> LDS (wave-uniform base + lane*16)
__device__ __forceinline__ void gl_lds16(const void* g, void* l) {
    __builtin_amdgcn_global_load_lds((const AS1 void*)(uintptr_t)g,
                                     (AS3 void*)(uintptr_t)l, 16, 0, 0);
}

// ---------------------------------------------------------------------------
// Top-k spatial neighbours: one WAVE per token, barrier-free shuffle argmin.
// Key = (f32bits(d2)<<32)|m : min key == min distance, tie -> lowest index.
// Set-equality with jax.lax.top_k suffices (attention is permutation-
// invariant over the gathered key set).
// ---------------------------------------------------------------------------
__global__ __launch_bounds__(256)
void topk_kernel(const float* __restrict__ X, int* __restrict__ idx) {
    const int w = threadIdx.x >> 6;
    const int l = threadIdx.x & 63;
    const int n = blockIdx.x * 4 + w;

    const float x0 = X[n * 3 + 0], x1 = X[n * 3 + 1], x2 = X[n * 3 + 2];
    float d[16];
    unsigned long long lkey = ~0ull;
#pragma unroll
    for (int j = 0; j < 16; ++j) {
        int m = j * 64 + l;
        float dx = x0 - X[m * 3 + 0];
        float dy = x1 - X[m * 3 + 1];
        float dz = x2 - X[m * 3 + 2];
        float v = dx * dx + dy * dy + dz * dz;
        d[j] = v;
        unsigned long long key =
            ((unsigned long long)__float_as_uint(v) << 32) | (unsigned int)m;
        lkey = key < lkey ? key : lkey;
    }
    if (l < NL) {
        int loc = n + l - NL / 2;
        loc = loc < 0 ? 0 : (loc > NTOK - 1 ? NTOK - 1 : loc);
        idx[n * KTOT + l] = loc;
    }

    for (int it = 0; it < NKEY; ++it) {
        unsigned long long rk = lkey;
#pragma unroll
        for (int s = 32; s > 0; s >>= 1) {
            unsigned long long o = __shfl_xor(rk, s, 64);
            rk = o < rk ? o : rk;
        }
        unsigned int win = (unsigned int)rk;
        if (l == 0) idx[n * KTOT + NL + it] = (int)win;
        if ((int)(win & 63) == l) {
            int jw = (int)(win >> 6);
            unsigned long long nk = ~0ull;
#pragma unroll
            for (int j = 0; j < 16; ++j) {
                if (j == jw) d[j] = INFINITY;
                unsigned long long key =
                    ((unsigned long long)__float_as_uint(d[j]) << 32) |
                    (unsigned int)(j * 64 + l);
                nk = key < nk ? key : nk;
            }
            lkey = nk;
        }
    }
}

// ---------------------------------------------------------------------------
// Row LayerNorm (no affine), fp32 out — used for S_I only
// ---------------------------------------------------------------------------
__global__ __launch_bounds__(256)
void ln_kernel(const float* __restrict__ in, float* __restrict__ out, int C) {
    int row = blockIdx.x;
    int t = threadIdx.x;
    __shared__ float red[256];
    float vals[6];
    int cnt = 0;
    float s = 0.0f;
    for (int c = t; c < C; c += 256) { float v = in[row * C + c]; vals[cnt++] = v; s += v; }
    red[t] = s; __syncthreads();
    for (int st = 128; st > 0; st >>= 1) { if (t < st) red[t] += red[t + st]; __syncthreads(); }
    float mean = red[0] / C;
    __syncthreads();
    float s2 = 0.0f;
    for (int j = 0; j < cnt; ++j) { float d = vals[j] - mean; s2 += d * d; }
    red[t] = s2; __syncthreads();
    for (int st = 128; st > 0; st >>= 1) { if (t < st) red[t] += red[t + st]; __syncthreads(); }
    float rstd = rsqrtf(red[0] / C + 1e-5f);
    for (int j = 0; j < cnt; ++j) {
        int c = t + j * 256;
        out[row * C + c] = (vals[j] - mean) * rstd;
    }
}

// ---------------------------------------------------------------------------
// Per-row LN stats of A [1024][768] -> stats[row] = {mean, rstd}
// ---------------------------------------------------------------------------
__global__ __launch_bounds__(256)
void lnstats_kernel(const float* __restrict__ in, float* __restrict__ stats) {
    int row = blockIdx.x;
    int t = threadIdx.x;
    __shared__ float red[256];
    float v0 = in[row * CT + t];
    float v1 = in[row * CT + t + 256];
    float v2 = in[row * CT + t + 512];
    red[t] = v0 + v1 + v2; __syncthreads();
    for (int st = 128; st > 0; st >>= 1) { if (t < st) red[t] += red[t + st]; __syncthreads(); }
    float mean = red[0] * (1.0f / CT);
    __syncthreads();
    float d0 = v0 - mean, d1 = v1 - mean, d2 = v2 - mean;
    red[t] = d0 * d0 + d1 * d1 + d2 * d2; __syncthreads();
    for (int st = 128; st > 0; st >>= 1) { if (t < st) red[t] += red[t + st]; __syncthreads(); }
    if (t == 0) {
        stats[row * 2] = mean;
        stats[row * 2 + 1] = rsqrtf(red[0] * (1.0f / CT) + 1e-5f);
    }
}

// ---------------------------------------------------------------------------
// Weight convert + transpose: fp32 [K][N] -> bf16 [N][K]
// ---------------------------------------------------------------------------
struct ConvDesc { const float* src; __hip_bfloat16* dst; int K; int N; int tstart; };
struct ConvTable { ConvDesc e[14]; };

__global__ __launch_bounds__(256)
void convT_kernel(ConvTable tab) {
    int b = blockIdx.x;
    int ei = 0;
#pragma unroll
    for (int j = 1; j < 14; ++j) if (b >= tab.e[j].tstart) ei = j;
    ConvDesc d = tab.e[ei];
    int tt = b - d.tstart;
    int ntn = d.N / 32;
    int k0 = (tt / ntn) * 32, n0 = (tt % ntn) * 32;
    __shared__ float s[32][33];
    int tx = threadIdx.x & 31, ty = threadIdx.x >> 5;
#pragma unroll
    for (int i = 0; i < 4; ++i)
        s[ty + 8 * i][tx] = d.src[(size_t)(k0 + ty + 8 * i) * d.N + n0 + tx];
    __syncthreads();
#pragma unroll
    for (int i = 0; i < 4; ++i)
        d.dst[(size_t)(n0 + ty + 8 * i) * d.K + k0 + tx] = __float2bfloat16(s[tx][ty + 8 * i]);
}

// ---------------------------------------------------------------------------
// Small prep kernels
// ---------------------------------------------------------------------------
__global__ __launch_bounds__(256)
void biasprep_kernel(const float* __restrict__ bq, const float* __restrict__ sg_b,
                     const float* __restrict__ tsg_b, float* __restrict__ qb,
                     float* __restrict__ sb2) {
    int t = blockIdx.x * 256 + threadIdx.x;
    if (t < NBLK * 3072) {
        int i = t / 3072, c = t % 3072;
        qb[t] = (c < 768) ? bq[i * 768 + c] : 0.0f;
    }
    if (t < NBLK * 1536) {
        int i = t / 1536, c = t % 1536;
        sb2[t] = (c < 768) ? sg_b[i * 768 + c] : tsg_b[i * 768 + c - 768];
    }
}

__global__ __launch_bounds__(256)
void snb_kernel(const float* __restrict__ LNS, const float* __restrict__ g1,
                const float* __restrict__ g2, __hip_bfloat16* __restrict__ snb) {
    int t = blockIdx.x * 256 + threadIdx.x;
    int j = t / (NTOK * CS);
    int rc = t % (NTOK * CS);
    int c = rc % CS;
    const float* g = ((j & 1) ? g2 : g1) + (j >> 1) * CS;
    snb[t] = __float2bfloat16(LNS[rc] * g[c]);
}

__global__ __launch_bounds__(256)
void tobf_kernel(const float* __restrict__ in, __hip_bfloat16* __restrict__ out) {
    int t = blockIdx.x * 256 + threadIdx.x;
    out[t] = __float2bfloat16(in[t]);
}

// ---------------------------------------------------------------------------
// bf16 MFMA GEMM: tile 64x64, BK=64, 4 waves (2x2), wave does 32x32.
// LDS XOR-swizzled: pre-swizzled global source for global_load_lds (linear
// dest) + swizzled ds_read (rule #21-correct).
// MODE 0: outf = acc1 + cbias[col]                              (fp32)
// MODE 1: outb = bf16( sigmoid(acc1+cbias)*LN(aux;stats) + acc2 )
// MODE 2: outb = bf16( silu(acc1) * acc2 )
// MODE 3: outf += sigmoid(aux) * acc1
// MODE 4: outb = bf16( acc1 + cbias[col] )
// ---------------------------------------------------------------------------
template <int MODE>
__global__ __launch_bounds__(256)
void gemm_kernel(const __hip_bfloat16* __restrict__ A,
                 const __hip_bfloat16* __restrict__ B1,
                 const __hip_bfloat16* __restrict__ B2,
                 const float* __restrict__ cbias,
                 const float* __restrict__ aux, int ld_aux,
                 const float* __restrict__ stats,
                 float* __restrict__ outf, __hip_bfloat16* __restrict__ outb,
                 int K, int N, int ldo) {
    constexpr bool DUAL = (MODE == 1 || MODE == 2);
    __shared__ __align__(16) char As[8192];
    __shared__ __align__(16) char Bs[8192];
    __shared__ __align__(16) char Bs2[DUAL ? 8192 : 16];

    const int tid = threadIdx.x;
    const int lane = tid & 63;
    const int wid = tid >> 6;
    const int wr = wid >> 1, wc = wid & 1;
    const int row0 = blockIdx.y * 64;
    const int col0 = blockIdx.x * 64;

    const int srow = tid >> 3;
    const int sg_e = (((tid & 7) ^ (srow & 7)) << 3);
    const __hip_bfloat16* ag = A + (size_t)(row0 + srow) * K + sg_e;
    const __hip_bfloat16* bg = B1 + (size_t)(col0 + srow) * K + sg_e;
    const __hip_bfloat16* bg2 = DUAL ? (B2 + (size_t)(col0 + srow) * K + sg_e) : nullptr;
    const size_t r32K = (size_t)32 * K;
    char* alds = As + tid * 16;
    char* blds = Bs + tid * 16;
    char* blds2 = Bs2 + tid * 16;

    f32x4 acc[2][2];
    f32x4 acc2[2][2];
#pragma unroll
    for (int i = 0; i < 2; ++i)
#pragma unroll
        for (int j = 0; j < 2; ++j) {
            acc[i][j] = (f32x4){0.f, 0.f, 0.f, 0.f};
            acc2[i][j] = (f32x4){0.f, 0.f, 0.f, 0.f};
        }

    const int l15 = lane & 15;
    const int lhi = lane >> 4;

    for (int k0 = 0; k0 < K; k0 += 64) {
        gl_lds16(ag, alds); gl_lds16(ag + r32K, alds + 4096);
        gl_lds16(bg, blds); gl_lds16(bg + r32K, blds + 4096);
        if (DUAL) { gl_lds16(bg2, blds2); gl_lds16(bg2 + r32K, blds2 + 4096); }
        ag += 64; bg += 64; if (DUAL) bg2 += 64;
        __syncthreads();
#pragma unroll
        for (int kk = 0; kk < 2; ++kk) {
            const int c = lhi + 4 * kk;
            const int ra0 = wr * 32 + l15, ra1 = ra0 + 16;
            const int rb0 = wc * 32 + l15, rb1 = rb0 + 16;
            short8 a0 = *(const short8*)(As + ra0 * 128 + (((c ^ (ra0 & 7)) << 4)));
            short8 a1 = *(const short8*)(As + ra1 * 128 + (((c ^ (ra1 & 7)) << 4)));
            short8 b0 = *(const short8*)(Bs + rb0 * 128 + (((c ^ (rb0 & 7)) << 4)));
            short8 b1 = *(const short8*)(Bs + rb1 * 128 + (((c ^ (rb1 & 7)) << 4)));
            acc[0][0] = __builtin_amdgcn_mfma_f32_16x16x32_bf16(a0, b0, acc[0][0], 0, 0, 0);
            acc[0][1] = __builtin_amdgcn_mfma_f32_16x16x32_bf16(a0, b1, acc[0][1], 0, 0, 0);
            acc[1][0] = __builtin_amdgcn_mfma_f32_16x16x32_bf16(a1, b0, acc[1][0], 0, 0, 0);
            acc[1][1] = __builtin_amdgcn_mfma_f32_16x16x32_bf16(a1, b1, acc[1][1], 0, 0, 0);
            if (DUAL) {
                short8 c0 = *(const short8*)(Bs2 + rb0 * 128 + (((c ^ (rb0 & 7)) << 4)));
                short8 c1 = *(const short8*)(Bs2 + rb1 * 128 + (((c ^ (rb1 & 7)) << 4)));
                acc2[0][0] = __builtin_amdgcn_mfma_f32_16x16x32_bf16(a0, c0, acc2[0][0], 0, 0, 0);
                acc2[0][1] = __builtin_amdgcn_mfma_f32_16x16x32_bf16(a0, c1, acc2[0][1], 0, 0, 0);
                acc2[1][0] = __builtin_amdgcn_mfma_f32_16x16x32_bf16(a1, c0, acc2[1][0], 0, 0, 0);
                acc2[1][1] = __builtin_amdgcn_mfma_f32_16x16x32_bf16(a1, c1, acc2[1][1], 0, 0, 0);
            }
        }
        __syncthreads();
    }

#pragma unroll
    for (int mi = 0; mi < 2; ++mi)
#pragma unroll
        for (int ni = 0; ni < 2; ++ni) {
            f32x4 v1 = acc[mi][ni];
            f32x4 v2 = acc2[mi][ni];
            int col = col0 + wc * 32 + ni * 16 + l15;
            int rbase = row0 + wr * 32 + mi * 16 + lhi * 4;
#pragma unroll
            for (int r = 0; r < 4; ++r) {
                int row = rbase + r;
                size_t o = (size_t)row * ldo + col;
                if (MODE == 0) {
                    outf[o] = v1[r] + (cbias ? cbias[col] : 0.0f);
                } else if (MODE == 1) {
                    float mean = stats[row * 2], rstd = stats[row * 2 + 1];
                    float anv = (aux[(size_t)row * ld_aux + col] - mean) * rstd;
                    float g = sigmoidf_(v1[r] + cbias[col]);
                    outb[o] = __float2bfloat16(g * anv + v2[r]);
                } else if (MODE == 2) {
                    float x = v1[r];
                    outb[o] = __float2bfloat16(x * sigmoidf_(x) * v2[r]);
                } else if (MODE == 3) {
                    outf[o] += sigmoidf_(aux[(size_t)row * ld_aux + col]) * v1[r];
                } else {
                    outb[o] = __float2bfloat16(v1[r] + cbias[col]);
                }
            }
        }
}

// ---------------------------------------------------------------------------
// Attention + fused pair bias. One block per token. bf16 qkvg [1024][3072].
// Phase 0: stage q, idx, Wb, pg/pb.  Phase 1: LN(z) rows (t<40).
// Phase 2: scores (QK + bias dot).   Phase 3: wave-parallel softmax.
// Phase 4: vectorized PV + gate (16B loads/stores).
// ---------------------------------------------------------------------------
__global__ __launch_bounds__(256)
void attn_kernel(const __hip_bfloat16* __restrict__ qkvg,
                 const float* __restrict__ Z,
                 const int* __restrict__ idx,
                 const float* __restrict__ pg, const float* __restrict__ pb,
                 const float* __restrict__ Wbp,
                 __hip_bfloat16* __restrict__ o2) {
    int n = blockIdx.x;
    int t = threadIdx.x;
    __shared__ __align__(16) unsigned short qs[768];
    __shared__ float sc[16][48];
    __shared__ float lnz[KTOT][16];
    __shared__ float wb[16][17];
    __shared__ float pgs[16], pbs[16];
    __shared__ int sidx[KTOT];

    wb[t >> 4][t & 15] = Wbp[t];
    if (t < 96) ((short8*)qs)[t] = ((const short8*)(qkvg + (size_t)n * 3072))[t];
    if (t >= 96 && t < 96 + KTOT) sidx[t - 96] = idx[n * KTOT + (t - 96)];
    if (t >= 160 && t < 176) pgs[t - 160] = pg[t - 160];
    if (t >= 176 && t < 192) pbs[t - 176] = pb[t - 176];
    __syncthreads();

    // ---- LN of gathered pair rows ----
    if (t < KTOT) {
        const f32x4* z = (const f32x4*)(Z + ((size_t)n * NTOK + sidx[t]) * CP);
        f32x4 z0 = z[0], z1 = z[1], z2 = z[2], z3 = z[3];
        float v[16];
#pragma unroll
        for (int e = 0; e < 4; ++e) { v[e] = z0[e]; v[4 + e] = z1[e]; v[8 + e] = z2[e]; v[12 + e] = z3[e]; }
        float s = 0.0f;
#pragma unroll
        for (int c = 0; c < 16; ++c) s += v[c];
        float mean = s * (1.0f / 16.0f);
        float s2 = 0.0f;
#pragma unroll
        for (int c = 0; c < 16; ++c) { float d = v[c] - mean; s2 += d * d; }
        float rstd = rsqrtf(s2 * (1.0f / 16.0f) + 1e-5f);
#pragma unroll
        for (int c = 0; c < 16; ++c) lnz[t][c] = (v[c] - mean) * rstd * pgs[c] + pbs[c];
    }
    __syncthreads();

    // ---- scores: QK^T * scale + bias ----
    for (int task = t; task < NH * KTOT; task += 256) {
        int h = task / KTOT, k = task - h * KTOT;
        const short8* kp = (const short8*)((const unsigned short*)qkvg +
                                           (size_t)sidx[k] * 3072 + 768 + h * DH);
        const short8* qp = (const short8*)(qs + h * DH);
        float s = 0.0f;
#pragma unroll
        for (int j = 0; j < 6; ++j) {
            short8 kv = kp[j];
            short8 qv = qp[j];
#pragma unroll
            for (int e = 0; e < 8; ++e)
                s += bf2f((unsigned short)qv[e]) * bf2f((unsigned short)kv[e]);
        }
        float bias = 0.0f;
#pragma unroll
        for (int c = 0; c < 16; ++c) bias += lnz[k][c] * wb[c][h];
        sc[h][k] = s * SCALE_ + bias;
    }
    __syncthreads();

    // ---- softmax: 16 lanes per head ----
    {
        int h = t >> 4, l = t & 15;
        float v0 = sc[h][l];
        float v1 = sc[h][l + 16];
        float v2 = (l < 8) ? sc[h][l + 32] : -INFINITY;
        float mx = fmaxf(fmaxf(v0, v1), v2);
#pragma unroll
        for (int m = 8; m > 0; m >>= 1) mx = fmaxf(mx, __shfl_xor(mx, m, 16));
        float e0 = __expf(v0 - mx), e1 = __expf(v1 - mx);
        float e2 = (l < 8) ? __expf(v2 - mx) : 0.0f;
        float sm = e0 + e1 + e2;
#pragma unroll
        for (int m = 8; m > 0; m >>= 1) sm += __shfl_xor(sm, m, 16);
        float inv = 1.0f / sm;
        sc[h][l] = e0 * inv;
        sc[h][l + 16] = e1 * inv;
        if (l < 8) sc[h][l + 32] = e2 * inv;
    }
    __syncthreads();

    // ---- PV + gate, vectorized 8 dims/thread ----
    if (t < 96) {
        int h = t / 6, c6 = t - h * 6;
        int d0 = c6 * 8;
        const unsigned short* vbase = (const unsigned short*)qkvg + 1536 + h * DH + d0;
        float acc[8] = {0, 0, 0, 0, 0, 0, 0, 0};
        for (int k = 0; k < KTOT; ++k) {
            short8 vv = *(const short8*)(vbase + (size_t)sidx[k] * 3072);
            float w = sc[h][k];
#pragma unroll
            for (int e = 0; e < 8; ++e) acc[e] += w * bf2f((unsigned short)vv[e]);
        }
        short8 gv = *(const short8*)((const unsigned short*)qkvg +
                                     (size_t)n * 3072 + 2304 + h * DH + d0);
        short8 ov;
#pragma unroll
        for (int e = 0; e < 8; ++e) {
            float g = sigmoidf_(bf2f((unsigned short)gv[e]));
            ov[e] = (short)__bfloat16_as_ushort(__float2bfloat16(g * acc[e]));
        }
        *(short8*)((unsigned short*)o2 + (size_t)n * CT + h * DH + d0) = ov;
    }
}

// ---------------------------------------------------------------------------
// Host orchestration
// ---------------------------------------------------------------------------
extern "C" void kernel_launch(void* const* d_in, const int* in_sizes, int n_in,
                              void* d_out, int out_size, void* d_ws, size_t ws_size,
                              hipStream_t stream) {
    const float* A_I  = (const float*)d_in[0];
    const float* S_I  = (const float*)d_in[1];
    const float* Z_II = (const float*)d_in[2];
    const float* X_L  = (const float*)d_in[3];
    const float* aln1_sln_g = (const float*)d_in[5];
    const float* aln1_sw    = (const float*)d_in[6];
    const float* aln1_sb    = (const float*)d_in[7];
    const float* aln1_shw   = (const float*)d_in[8];
    const float* Wq  = (const float*)d_in[9];
    const float* bq  = (const float*)d_in[10];
    const float* Wk  = (const float*)d_in[11];
    const float* Wv  = (const float*)d_in[12];
    const float* pair_ln_g = (const float*)d_in[13];
    const float* pair_ln_b = (const float*)d_in[14];
    const float* Wbp = (const float*)d_in[15];
    const float* Wg  = (const float*)d_in[16];
    const float* Wo  = (const float*)d_in[17];
    const float* sg_w = (const float*)d_in[18];
    const float* sg_b = (const float*)d_in[19];
    const float* aln2_sln_g = (const float*)d_in[20];
    const float* aln2_sw    = (const float*)d_in[21];
    const float* aln2_sb    = (const float*)d_in[22];
    const float* aln2_shw   = (const float*)d_in[23];
    const float* t_w1 = (const float*)d_in[24];
    const float* t_w2 = (const float*)d_in[25];
    const float* t_w3 = (const float*)d_in[26];
    const float* tsg_w = (const float*)d_in[27];
    const float* tsg_b = (const float*)d_in[28];
    (void)in_sizes; (void)n_in; (void)out_size;

    float* A = (float*)d_out;

    char* ws = (char*)d_ws;
    size_t off = 0;
    auto alloc = [&](size_t bytes) {
        void* p = ws + off;
        off += (bytes + 255) & ~(size_t)255;
        return p;
    };
    int*   idx    = (int*)  alloc(NTOK * KTOT * 4);
    float* LNS    = (float*)alloc((size_t)NTOK * CS * 4);
    float* stats  = (float*)alloc((size_t)NTOK * 2 * 4);
    __hip_bfloat16* S_bf = (__hip_bfloat16*)alloc((size_t)NTOK * CS * 2);
    __hip_bfloat16* snb  = (__hip_bfloat16*)alloc((size_t)8 * NTOK * CS * 2);
    __hip_bfloat16* an   = (__hip_bfloat16*)alloc((size_t)NTOK * CT * 2);
    __hip_bfloat16* qkvg = (__hip_bfloat16*)alloc((size_t)NTOK * 3072 * 2);
    float* sg2    = (float*)alloc((size_t)NTOK * 1536 * 4);
    __hip_bfloat16* o2 = (__hip_bfloat16*)alloc((size_t)NTOK * CT * 2);
    __hip_bfloat16* hb = (__hip_bfloat16*)alloc((size_t)NTOK * 2 * CT * 2);
    float* qkvgbias = (float*)alloc((size_t)NBLK * 3072 * 4);
    float* sgbias   = (float*)alloc((size_t)NBLK * 1536 * 4);
    __hip_bfloat16* Wbuf = (__hip_bfloat16*)alloc((size_t)8257536 * 2);
    (void)ws_size;

    __hip_bfloat16* ALN1SW  = Wbuf + 0;
    __hip_bfloat16* ALN1SHW = Wbuf + 294912;
    __hip_bfloat16* QKVGT   = Wbuf + 589824;
    __hip_bfloat16* WOT     = Wbuf + 2949120;
    __hip_bfloat16* SGT     = Wbuf + 3538944;
    __hip_bfloat16* ALN2SW  = Wbuf + 4128768;
    __hip_bfloat16* ALN2SHW = Wbuf + 4423680;
    __hip_bfloat16* TW1T    = Wbuf + 4718592;
    __hip_bfloat16* TW2T    = Wbuf + 5898240;
    __hip_bfloat16* TW3T    = Wbuf + 7077888;

    hipMemcpyAsync(A, A_I, (size_t)NTOK * CT * 4, hipMemcpyDeviceToDevice, stream);

    topk_kernel<<<NTOK / 4, 256, 0, stream>>>(X_L, idx);
    ln_kernel<<<NTOK, 256, 0, stream>>>(S_I, LNS, CS);
    snb_kernel<<<8 * NTOK * CS / 256, 256, 0, stream>>>(LNS, aln1_sln_g, aln2_sln_g, snb);
    tobf_kernel<<<NTOK * CS / 256, 256, 0, stream>>>(S_I, S_bf);
    biasprep_kernel<<<NBLK * 3072 / 256, 256, 0, stream>>>(bq, sg_b, tsg_b, qkvgbias, sgbias);

    dim3 gAda(12, 16), gQKVG(48, 16), gSg(24, 16), gOut(12, 16), gTrans(24, 16);

    for (int i = 0; i < NBLK; ++i) {
        ConvTable tab;
        int p = 0, ts = 0;
        auto add = [&](const float* s, __hip_bfloat16* d, int Kk, int Nn) {
            tab.e[p].src = s; tab.e[p].dst = d; tab.e[p].K = Kk; tab.e[p].N = Nn;
            tab.e[p].tstart = ts; ts += (Kk / 32) * (Nn / 32); ++p;
        };
        add(aln1_sw  + (size_t)i * CS * CT, ALN1SW, 384, 768);
        add(aln1_shw + (size_t)i * CS * CT, ALN1SHW, 384, 768);
        add(Wq + (size_t)i * CT * CT, QKVGT + (size_t)0 * 768 * 768, 768, 768);
        add(Wk + (size_t)i * CT * CT, QKVGT + (size_t)1 * 768 * 768, 768, 768);
        add(Wv + (size_t)i * CT * CT, QKVGT + (size_t)2 * 768 * 768, 768, 768);
        add(Wg + (size_t)i * CT * CT, QKVGT + (size_t)3 * 768 * 768, 768, 768);
        add(Wo + (size_t)i * CT * CT, WOT, 768, 768);
        add(sg_w  + (size_t)i * CS * CT, SGT, 384, 768);
        add(tsg_w + (size_t)i * CS * CT, SGT + (size_t)768 * 384, 384, 768);
        add(aln2_sw  + (size_t)i * CS * CT, ALN2SW, 384, 768);
        add(aln2_shw + (size_t)i * CS * CT, ALN2SHW, 384, 768);
        add(t_w1 + (size_t)i * CT * 2 * CT, TW1T, 768, 1536);
        add(t_w2 + (size_t)i * CT * 2 * CT, TW2T, 768, 1536);
        add(t_w3 + (size_t)i * 2 * CT * CT, TW3T, 1536, 768);
        convT_kernel<<<ts, 256, 0, stream>>>(tab);

        // ---- LocalAttentionPairBias ----
        lnstats_kernel<<<NTOK, 256, 0, stream>>>(A, stats);
        gemm_kernel<1><<<gAda, 256, 0, stream>>>(
            snb + (size_t)(2 * i) * NTOK * CS, ALN1SW, ALN1SHW,
            aln1_sb + (size_t)i * CT, A, 768, stats, nullptr, an, 384, 768, 768);
        gemm_kernel<4><<<gQKVG, 256, 0, stream>>>(
            an, QKVGT, nullptr, qkvgbias + (size_t)i * 3072, nullptr, 0, nullptr,
            nullptr, qkvg, 768, 3072, 3072);
        gemm_kernel<0><<<gSg, 256, 0, stream>>>(
            S_bf, SGT, nullptr, sgbias + (size_t)i * 1536, nullptr, 0, nullptr,
            sg2, nullptr, 384, 1536, 1536);
        attn_kernel<<<NTOK, 256, 0, stream>>>(
            qkvg, Z_II, idx, pair_ln_g + (size_t)i * CP, pair_ln_b + (size_t)i * CP,
            Wbp + (size_t)i * CP * NH, o2);
        gemm_kernel<3><<<gOut, 256, 0, stream>>>(
            o2, WOT, nullptr, nullptr, sg2, 1536, nullptr, A, nullptr, 768, 768, 768);

        // ---- ConditionedTransitionBlock ----
        lnstats_kernel<<<NTOK, 256, 0, stream>>>(A, stats);
        gemm_kernel<1><<<gAda, 256, 0, stream>>>(
            snb + (size_t)(2 * i + 1) * NTOK * CS, ALN2SW, ALN2SHW,
            aln2_sb + (size_t)i * CT, A, 768, stats, nullptr, an, 384, 768, 768);
        gemm_kernel<2><<<gTrans, 256, 0, stream>>>(
            an, TW1T, TW2T, nullptr, nullptr, 0, nullptr, nullptr, hb, 768, 1536, 1536);
        gemm_kernel<3><<<gOut, 256, 0, stream>>>(
            hb, TW3T, nullptr, nullptr, sg2 + 768, 1536, nullptr, A, nullptr, 1536, 768, 768);
    }
}

// Round 6
// 448.037 us; speedup vs baseline: 6.3612x; 1.1576x over previous
//
#include <hip/hip_runtime.h>
#include <hip/hip_bf16.h>
#include <math.h>
#include <stdint.h>

#define NTOK 1024
#define CT   768
#define CS   384
#define CP   16
#define NH   16
#define DH   48
#define NBLK 4
#define NL   8
#define NKEY 32
#define KTOT 40
#define SCALE_ 0.14433756729740643f   // 1/sqrt(48)

// Wbuf per-block element offsets (bf16 elements)
#define WS_BLK      8257536
#define OFF_A1SW    0
#define OFF_A1SHW   294912
#define OFF_QKVG    589824
#define OFF_WO      2949120
#define OFF_SGT     3538944
#define OFF_A2SW    4128768
#define OFF_A2SHW   4423680
#define OFF_TW1     4718592
#define OFF_TW2     5898240
#define OFF_TW3     7077888

typedef __attribute__((ext_vector_type(8))) short short8;
typedef __attribute__((ext_vector_type(4))) float f32x4;

#define AS1 __attribute__((address_space(1)))
#define AS3 __attribute__((address_space(3)))

__device__ __forceinline__ float sigmoidf_(float x) {
    return 1.0f / (1.0f + __expf(-x));
}
__device__ __forceinline__ float bf2f(unsigned short u) {
    union { unsigned int i; float f; } v; v.i = (unsigned int)u << 16; return v.f;
}

__device__ __forceinline__ void gl_lds16(const void* g, void* l) {
    __builtin_amdgcn_global_load_lds((const AS1 void*)(uintptr_t)g,
                                     (AS3 void*)(uintptr_t)l, 16, 0, 0);
}

// ---------------------------------------------------------------------------
// Top-k spatial neighbours: one WAVE per token, barrier-free shuffle argmin.
// ---------------------------------------------------------------------------
__global__ __launch_bounds__(256)
void topk_kernel(const float* __restrict__ X, int* __restrict__ idx) {
    const int w = threadIdx.x >> 6;
    const int l = threadIdx.x & 63;
    const int n = blockIdx.x * 4 + w;

    const float x0 = X[n * 3 + 0], x1 = X[n * 3 + 1], x2 = X[n * 3 + 2];
    float d[16];
    unsigned long long lkey = ~0ull;
#pragma unroll
    for (int j = 0; j < 16; ++j) {
        int m = j * 64 + l;
        float dx = x0 - X[m * 3 + 0];
        float dy = x1 - X[m * 3 + 1];
        float dz = x2 - X[m * 3 + 2];
        float v = dx * dx + dy * dy + dz * dz;
        d[j] = v;
        unsigned long long key =
            ((unsigned long long)__float_as_uint(v) << 32) | (unsigned int)m;
        lkey = key < lkey ? key : lkey;
    }
    if (l < NL) {
        int loc = n + l - NL / 2;
        loc = loc < 0 ? 0 : (loc > NTOK - 1 ? NTOK - 1 : loc);
        idx[n * KTOT + l] = loc;
    }

    for (int it = 0; it < NKEY; ++it) {
        unsigned long long rk = lkey;
#pragma unroll
        for (int s = 32; s > 0; s >>= 1) {
            unsigned long long o = __shfl_xor(rk, s, 64);
            rk = o < rk ? o : rk;
        }
        unsigned int win = (unsigned int)rk;
        if (l == 0) idx[n * KTOT + NL + it] = (int)win;
        if ((int)(win & 63) == l) {
            int jw = (int)(win >> 6);
            unsigned long long nk = ~0ull;
#pragma unroll
            for (int j = 0; j < 16; ++j) {
                if (j == jw) d[j] = INFINITY;
                unsigned long long key =
                    ((unsigned long long)__float_as_uint(d[j]) << 32) |
                    (unsigned int)(j * 64 + l);
                nk = key < nk ? key : nk;
            }
            lkey = nk;
        }
    }
}

// ---------------------------------------------------------------------------
// S prep: LN(S_I) row (no affine), then S_bf = bf16(S_I) and
// snb[j] = bf16(LN(S)*g_j) for all 8 AdaLN sites. One block per row, 384 thr.
// ---------------------------------------------------------------------------
__global__ __launch_bounds__(384)
void sprep_kernel(const float* __restrict__ S, const float* __restrict__ g1,
                  const float* __restrict__ g2,
                  __hip_bfloat16* __restrict__ S_bf,
                  __hip_bfloat16* __restrict__ snb) {
    int r = blockIdx.x, t = threadIdx.x;
    int wid = t >> 6, l = t & 63;
    __shared__ float ls[12];
    float v = S[r * CS + t];
    float s = v;
#pragma unroll
    for (int m = 32; m > 0; m >>= 1) s += __shfl_xor(s, m, 64);
    if (l == 0) ls[wid] = s;
    __syncthreads();
    float mean = (ls[0] + ls[1] + ls[2] + ls[3] + ls[4] + ls[5]) * (1.0f / CS);
    float d = v - mean;
    float q = d * d;
#pragma unroll
    for (int m = 32; m > 0; m >>= 1) q += __shfl_xor(q, m, 64);
    if (l == 0) ls[6 + wid] = q;
    __syncthreads();
    float rstd = rsqrtf((ls[6] + ls[7] + ls[8] + ls[9] + ls[10] + ls[11]) *
                        (1.0f / CS) + 1e-5f);
    float ln = d * rstd;
    S_bf[r * CS + t] = __float2bfloat16(v);
#pragma unroll
    for (int j = 0; j < 8; ++j) {
        const float* g = ((j & 1) ? g2 : g1) + (j >> 1) * CS;
        snb[((size_t)j * NTOK + r) * CS + t] = __float2bfloat16(ln * g[t]);
    }
}

// ---------------------------------------------------------------------------
// AdaLN apply: an = bf16( sigmoid(SIG) * LN(A) + SH ). One block per row.
// ---------------------------------------------------------------------------
__global__ __launch_bounds__(256)
void adaapply_kernel(const float* __restrict__ A,
                     const __hip_bfloat16* __restrict__ SIG,
                     const __hip_bfloat16* __restrict__ SH,
                     __hip_bfloat16* __restrict__ an) {
    int r = blockIdx.x, t = threadIdx.x;
    int wid = t >> 6, l = t & 63;
    __shared__ float ls[8];
    const float* ar = A + (size_t)r * CT;
    float v0 = ar[t], v1 = ar[t + 256], v2 = ar[t + 512];
    float s = v0 + v1 + v2;
#pragma unroll
    for (int m = 32; m > 0; m >>= 1) s += __shfl_xor(s, m, 64);
    if (l == 0) ls[wid] = s;
    __syncthreads();
    float mean = (ls[0] + ls[1] + ls[2] + ls[3]) * (1.0f / CT);
    float d0 = v0 - mean, d1 = v1 - mean, d2 = v2 - mean;
    float q = d0 * d0 + d1 * d1 + d2 * d2;
#pragma unroll
    for (int m = 32; m > 0; m >>= 1) q += __shfl_xor(q, m, 64);
    if (l == 0) ls[4 + wid] = q;
    __syncthreads();
    float rstd = rsqrtf((ls[4] + ls[5] + ls[6] + ls[7]) * (1.0f / CT) + 1e-5f);
    size_t base = (size_t)r * CT;
    float dd[3] = {d0, d1, d2};
#pragma unroll
    for (int k = 0; k < 3; ++k) {
        int c = t + k * 256;
        float sg = sigmoidf_(__bfloat162float(SIG[base + c]));
        float sh = __bfloat162float(SH[base + c]);
        an[base + c] = __float2bfloat16(sg * dd[k] * rstd + sh);
    }
}

// ---------------------------------------------------------------------------
// Weight convert + transpose: fp32 [K][N] -> bf16 [N][K]; all 4 blocks via
// grid.y (src += y*srcStride, dst += y*WS_BLK).
// ---------------------------------------------------------------------------
struct ConvDesc { const float* src; __hip_bfloat16* dst; int K; int N; int tstart; int srcStride; };
struct ConvTable { ConvDesc e[14]; };

__global__ __launch_bounds__(256)
void convT_kernel(ConvTable tab) {
    int b = blockIdx.x;
    int ei = 0;
#pragma unroll
    for (int j = 1; j < 14; ++j) if (b >= tab.e[j].tstart) ei = j;
    ConvDesc d = tab.e[ei];
    const float* src = d.src + (size_t)blockIdx.y * d.srcStride;
    __hip_bfloat16* dst = d.dst + (size_t)blockIdx.y * WS_BLK;
    int tt = b - d.tstart;
    int ntn = d.N / 32;
    int k0 = (tt / ntn) * 32, n0 = (tt % ntn) * 32;
    __shared__ float s[32][33];
    int tx = threadIdx.x & 31, ty = threadIdx.x >> 5;
#pragma unroll
    for (int i = 0; i < 4; ++i)
        s[ty + 8 * i][tx] = src[(size_t)(k0 + ty + 8 * i) * d.N + n0 + tx];
    __syncthreads();
#pragma unroll
    for (int i = 0; i < 4; ++i)
        dst[(size_t)(n0 + ty + 8 * i) * d.K + k0 + tx] = __float2bfloat16(s[tx][ty + 8 * i]);
}

__global__ __launch_bounds__(256)
void biasprep_kernel(const float* __restrict__ bq, const float* __restrict__ sg_b,
                     const float* __restrict__ tsg_b, float* __restrict__ qb,
                     float* __restrict__ sb2) {
    int t = blockIdx.x * 256 + threadIdx.x;
    if (t < NBLK * 3072) {
        int i = t / 3072, c = t % 3072;
        qb[t] = (c < 768) ? bq[i * 768 + c] : 0.0f;
    }
    if (t < NBLK * 1536) {
        int i = t / 1536, c = t % 1536;
        sb2[t] = (c < 768) ? sg_b[i * 768 + c] : tsg_b[i * 768 + c - 768];
    }
}

// ---------------------------------------------------------------------------
// bf16 MFMA GEMM: tile 64x64, BK=64, 4 waves (2x2), XOR-swizzled LDS.
// MODE 2: outb = bf16( silu(acc1) * acc2 )                 (trans, DUAL)
// MODE 3: outf += sigmoid(auxb) * acc1                     (gated residual)
// MODE 4: outb = bf16( acc1 + cb[col] )                    (QKVG)
// MODE 5: grouped z=8 AdaLN-pre: outb=bf16(acc1+cb), outb2=bf16(acc2) (DUAL)
// MODE 6: grouped z=4 sgate-pre: outb = bf16( acc1 + cb )
// ---------------------------------------------------------------------------
template <int MODE>
__global__ __launch_bounds__(256)
void gemm_kernel(const __hip_bfloat16* __restrict__ A,
                 const __hip_bfloat16* B1,
                 const __hip_bfloat16* B2,
                 const float* __restrict__ cb1,
                 const float* __restrict__ cb2,
                 const __hip_bfloat16* __restrict__ auxb, int ld_aux,
                 float* __restrict__ outf,
                 __hip_bfloat16* outb,
                 __hip_bfloat16* outb2,
                 int K, int N, int ldo) {
    constexpr bool DUAL = (MODE == 2 || MODE == 5);
    __shared__ __align__(16) char As[8192];
    __shared__ __align__(16) char Bs[8192];
    __shared__ __align__(16) char Bs2[DUAL ? 8192 : 16];

    const float* cb = cb1;
    if constexpr (MODE == 5) {
        size_t z = blockIdx.z;
        A += z * (size_t)(NTOK * CS);
        B1 += (z >> 1) * (size_t)WS_BLK + (z & 1) * (size_t)OFF_A2SW;
        B2 = B1 + OFF_A1SHW;
        cb = ((z & 1) ? cb2 : cb1) + (z >> 1) * CT;
        outb += z * (size_t)(NTOK * CT);
        outb2 += z * (size_t)(NTOK * CT);
    } else if constexpr (MODE == 6) {
        size_t z = blockIdx.z;
        B1 += z * (size_t)WS_BLK;
        cb = cb1 + z * 1536;
        outb += z * (size_t)(NTOK * 1536);
    }

    const int tid = threadIdx.x;
    const int lane = tid & 63;
    const int wid = tid >> 6;
    const int wr = wid >> 1, wc = wid & 1;
    const int row0 = blockIdx.y * 64;
    const int col0 = blockIdx.x * 64;

    const int srow = tid >> 3;
    const int sg_e = (((tid & 7) ^ (srow & 7)) << 3);
    const __hip_bfloat16* ag = A + (size_t)(row0 + srow) * K + sg_e;
    const __hip_bfloat16* bg = B1 + (size_t)(col0 + srow) * K + sg_e;
    const __hip_bfloat16* bg2 = DUAL ? (B2 + (size_t)(col0 + srow) * K + sg_e) : nullptr;
    const size_t r32K = (size_t)32 * K;
    char* alds = As + tid * 16;
    char* blds = Bs + tid * 16;
    char* blds2 = Bs2 + tid * 16;

    f32x4 acc[2][2];
    f32x4 acc2[2][2];
#pragma unroll
    for (int i = 0; i < 2; ++i)
#pragma unroll
        for (int j = 0; j < 2; ++j) {
            acc[i][j] = (f32x4){0.f, 0.f, 0.f, 0.f};
            acc2[i][j] = (f32x4){0.f, 0.f, 0.f, 0.f};
        }

    const int l15 = lane & 15;
    const int lhi = lane >> 4;

    for (int k0 = 0; k0 < K; k0 += 64) {
        gl_lds16(ag, alds); gl_lds16(ag + r32K, alds + 4096);
        gl_lds16(bg, blds); gl_lds16(bg + r32K, blds + 4096);
        if (DUAL) { gl_lds16(bg2, blds2); gl_lds16(bg2 + r32K, blds2 + 4096); }
        ag += 64; bg += 64; if (DUAL) bg2 += 64;
        __syncthreads();
#pragma unroll
        for (int kk = 0; kk < 2; ++kk) {
            const int c = lhi + 4 * kk;
            const int ra0 = wr * 32 + l15, ra1 = ra0 + 16;
            const int rb0 = wc * 32 + l15, rb1 = rb0 + 16;
            short8 a0 = *(const short8*)(As + ra0 * 128 + (((c ^ (ra0 & 7)) << 4)));
            short8 a1 = *(const short8*)(As + ra1 * 128 + (((c ^ (ra1 & 7)) << 4)));
            short8 b0 = *(const short8*)(Bs + rb0 * 128 + (((c ^ (rb0 & 7)) << 4)));
            short8 b1 = *(const short8*)(Bs + rb1 * 128 + (((c ^ (rb1 & 7)) << 4)));
            acc[0][0] = __builtin_amdgcn_mfma_f32_16x16x32_bf16(a0, b0, acc[0][0], 0, 0, 0);
            acc[0][1] = __builtin_amdgcn_mfma_f32_16x16x32_bf16(a0, b1, acc[0][1], 0, 0, 0);
            acc[1][0] = __builtin_amdgcn_mfma_f32_16x16x32_bf16(a1, b0, acc[1][0], 0, 0, 0);
            acc[1][1] = __builtin_amdgcn_mfma_f32_16x16x32_bf16(a1, b1, acc[1][1], 0, 0, 0);
            if (DUAL) {
                short8 c0 = *(const short8*)(Bs2 + rb0 * 128 + (((c ^ (rb0 & 7)) << 4)));
                short8 c1 = *(const short8*)(Bs2 + rb1 * 128 + (((c ^ (rb1 & 7)) << 4)));
                acc2[0][0] = __builtin_amdgcn_mfma_f32_16x16x32_bf16(a0, c0, acc2[0][0], 0, 0, 0);
                acc2[0][1] = __builtin_amdgcn_mfma_f32_16x16x32_bf16(a0, c1, acc2[0][1], 0, 0, 0);
                acc2[1][0] = __builtin_amdgcn_mfma_f32_16x16x32_bf16(a1, c0, acc2[1][0], 0, 0, 0);
                acc2[1][1] = __builtin_amdgcn_mfma_f32_16x16x32_bf16(a1, c1, acc2[1][1], 0, 0, 0);
            }
        }
        __syncthreads();
    }

#pragma unroll
    for (int mi = 0; mi < 2; ++mi)
#pragma unroll
        for (int ni = 0; ni < 2; ++ni) {
            f32x4 v1 = acc[mi][ni];
            f32x4 v2 = acc2[mi][ni];
            int col = col0 + wc * 32 + ni * 16 + l15;
            int rbase = row0 + wr * 32 + mi * 16 + lhi * 4;
#pragma unroll
            for (int r = 0; r < 4; ++r) {
                int row = rbase + r;
                size_t o = (size_t)row * ldo + col;
                if (MODE == 2) {
                    float x = v1[r];
                    outb[o] = __float2bfloat16(x * sigmoidf_(x) * v2[r]);
                } else if (MODE == 3) {
                    float g = sigmoidf_(__bfloat162float(auxb[(size_t)row * ld_aux + col]));
                    outf[o] += g * v1[r];
                } else if (MODE == 4 || MODE == 6) {
                    outb[o] = __float2bfloat16(v1[r] + cb[col]);
                } else {  // MODE 5
                    outb[o] = __float2bfloat16(v1[r] + cb[col]);
                    outb2[o] = __float2bfloat16(v2[r]);
                }
            }
        }
}

// ---------------------------------------------------------------------------
// Attention + fused pair bias. One block per token. bf16 qkvg [1024][3072].
// ---------------------------------------------------------------------------
__global__ __launch_bounds__(256)
void attn_kernel(const __hip_bfloat16* __restrict__ qkvg,
                 const float* __restrict__ Z,
                 const int* __restrict__ idx,
                 const float* __restrict__ pg, const float* __restrict__ pb,
                 const float* __restrict__ Wbp,
                 __hip_bfloat16* __restrict__ o2) {
    int n = blockIdx.x;
    int t = threadIdx.x;
    __shared__ __align__(16) unsigned short qs[768];
    __shared__ float sc[16][48];
    __shared__ float lnz[KTOT][16];
    __shared__ float wb[16][17];
    __shared__ float pgs[16], pbs[16];
    __shared__ int sidx[KTOT];

    wb[t >> 4][t & 15] = Wbp[t];
    if (t < 96) ((short8*)qs)[t] = ((const short8*)(qkvg + (size_t)n * 3072))[t];
    if (t >= 96 && t < 96 + KTOT) sidx[t - 96] = idx[n * KTOT + (t - 96)];
    if (t >= 160 && t < 176) pgs[t - 160] = pg[t - 160];
    if (t >= 176 && t < 192) pbs[t - 176] = pb[t - 176];
    __syncthreads();

    if (t < KTOT) {
        const f32x4* z = (const f32x4*)(Z + ((size_t)n * NTOK + sidx[t]) * CP);
        f32x4 z0 = z[0], z1 = z[1], z2 = z[2], z3 = z[3];
        float v[16];
#pragma unroll
        for (int e = 0; e < 4; ++e) { v[e] = z0[e]; v[4 + e] = z1[e]; v[8 + e] = z2[e]; v[12 + e] = z3[e]; }
        float s = 0.0f;
#pragma unroll
        for (int c = 0; c < 16; ++c) s += v[c];
        float mean = s * (1.0f / 16.0f);
        float s2 = 0.0f;
#pragma unroll
        for (int c = 0; c < 16; ++c) { float d = v[c] - mean; s2 += d * d; }
        float rstd = rsqrtf(s2 * (1.0f / 16.0f) + 1e-5f);
#pragma unroll
        for (int c = 0; c < 16; ++c) lnz[t][c] = (v[c] - mean) * rstd * pgs[c] + pbs[c];
    }
    __syncthreads();

    for (int task = t; task < NH * KTOT; task += 256) {
        int h = task / KTOT, k = task - h * KTOT;
        const short8* kp = (const short8*)((const unsigned short*)qkvg +
                                           (size_t)sidx[k] * 3072 + 768 + h * DH);
        const short8* qp = (const short8*)(qs + h * DH);
        float s = 0.0f;
#pragma unroll
        for (int j = 0; j < 6; ++j) {
            short8 kv = kp[j];
            short8 qv = qp[j];
#pragma unroll
            for (int e = 0; e < 8; ++e)
                s += bf2f((unsigned short)qv[e]) * bf2f((unsigned short)kv[e]);
        }
        float bias = 0.0f;
#pragma unroll
        for (int c = 0; c < 16; ++c) bias += lnz[k][c] * wb[c][h];
        sc[h][k] = s * SCALE_ + bias;
    }
    __syncthreads();

    {
        int h = t >> 4, l = t & 15;
        float v0 = sc[h][l];
        float v1 = sc[h][l + 16];
        float v2 = (l < 8) ? sc[h][l + 32] : -INFINITY;
        float mx = fmaxf(fmaxf(v0, v1), v2);
#pragma unroll
        for (int m = 8; m > 0; m >>= 1) mx = fmaxf(mx, __shfl_xor(mx, m, 16));
        float e0 = __expf(v0 - mx), e1 = __expf(v1 - mx);
        float e2 = (l < 8) ? __expf(v2 - mx) : 0.0f;
        float sm = e0 + e1 + e2;
#pragma unroll
        for (int m = 8; m > 0; m >>= 1) sm += __shfl_xor(sm, m, 16);
        float inv = 1.0f / sm;
        sc[h][l] = e0 * inv;
        sc[h][l + 16] = e1 * inv;
        if (l < 8) sc[h][l + 32] = e2 * inv;
    }
    __syncthreads();

    if (t < 96) {
        int h = t / 6, c6 = t - h * 6;
        int d0 = c6 * 8;
        const unsigned short* vbase = (const unsigned short*)qkvg + 1536 + h * DH + d0;
        float acc[8] = {0, 0, 0, 0, 0, 0, 0, 0};
        for (int k = 0; k < KTOT; ++k) {
            short8 vv = *(const short8*)(vbase + (size_t)sidx[k] * 3072);
            float w = sc[h][k];
#pragma unroll
            for (int e = 0; e < 8; ++e) acc[e] += w * bf2f((unsigned short)vv[e]);
        }
        short8 gv = *(const short8*)((const unsigned short*)qkvg +
                                     (size_t)n * 3072 + 2304 + h * DH + d0);
        short8 ov;
#pragma unroll
        for (int e = 0; e < 8; ++e) {
            float g = sigmoidf_(bf2f((unsigned short)gv[e]));
            ov[e] = (short)__bfloat16_as_ushort(__float2bfloat16(g * acc[e]));
        }
        *(short8*)((unsigned short*)o2 + (size_t)n * CT + h * DH + d0) = ov;
    }
}

// ---------------------------------------------------------------------------
// Host orchestration
// ---------------------------------------------------------------------------
extern "C" void kernel_launch(void* const* d_in, const int* in_sizes, int n_in,
                              void* d_out, int out_size, void* d_ws, size_t ws_size,
                              hipStream_t stream) {
    const float* A_I  = (const float*)d_in[0];
    const float* S_I  = (const float*)d_in[1];
    const float* Z_II = (const float*)d_in[2];
    const float* X_L  = (const float*)d_in[3];
    const float* aln1_sln_g = (const float*)d_in[5];
    const float* aln1_sw    = (const float*)d_in[6];
    const float* aln1_sb    = (const float*)d_in[7];
    const float* aln1_shw   = (const float*)d_in[8];
    const float* Wq  = (const float*)d_in[9];
    const float* bq  = (const float*)d_in[10];
    const float* Wk  = (const float*)d_in[11];
    const float* Wv  = (const float*)d_in[12];
    const float* pair_ln_g = (const float*)d_in[13];
    const float* pair_ln_b = (const float*)d_in[14];
    const float* Wbp = (const float*)d_in[15];
    const float* Wg  = (const float*)d_in[16];
    const float* Wo  = (const float*)d_in[17];
    const float* sg_w = (const float*)d_in[18];
    const float* sg_b = (const float*)d_in[19];
    const float* aln2_sln_g = (const float*)d_in[20];
    const float* aln2_sw    = (const float*)d_in[21];
    const float* aln2_sb    = (const float*)d_in[22];
    const float* aln2_shw   = (const float*)d_in[23];
    const float* t_w1 = (const float*)d_in[24];
    const float* t_w2 = (const float*)d_in[25];
    const float* t_w3 = (const float*)d_in[26];
    const float* tsg_w = (const float*)d_in[27];
    const float* tsg_b = (const float*)d_in[28];
    (void)in_sizes; (void)n_in; (void)out_size; (void)ws_size;

    float* A = (float*)d_out;

    char* ws = (char*)d_ws;
    size_t off = 0;
    auto alloc = [&](size_t bytes) {
        void* p = ws + off;
        off += (bytes + 255) & ~(size_t)255;
        return p;
    };
    int*   idx    = (int*)  alloc(NTOK * KTOT * 4);
    __hip_bfloat16* S_bf  = (__hip_bfloat16*)alloc((size_t)NTOK * CS * 2);
    __hip_bfloat16* snb   = (__hip_bfloat16*)alloc((size_t)8 * NTOK * CS * 2);
    __hip_bfloat16* an    = (__hip_bfloat16*)alloc((size_t)NTOK * CT * 2);
    __hip_bfloat16* qkvg  = (__hip_bfloat16*)alloc((size_t)NTOK * 3072 * 2);
    __hip_bfloat16* sgateb= (__hip_bfloat16*)alloc((size_t)NBLK * NTOK * 1536 * 2);
    __hip_bfloat16* SIG   = (__hip_bfloat16*)alloc((size_t)8 * NTOK * CT * 2);
    __hip_bfloat16* SH    = (__hip_bfloat16*)alloc((size_t)8 * NTOK * CT * 2);
    __hip_bfloat16* o2    = (__hip_bfloat16*)alloc((size_t)NTOK * CT * 2);
    __hip_bfloat16* hb    = (__hip_bfloat16*)alloc((size_t)NTOK * 2 * CT * 2);
    float* qkvgbias = (float*)alloc((size_t)NBLK * 3072 * 4);
    float* sgbias   = (float*)alloc((size_t)NBLK * 1536 * 4);
    __hip_bfloat16* Wbuf = (__hip_bfloat16*)alloc((size_t)NBLK * WS_BLK * 2);

    hipMemcpyAsync(A, A_I, (size_t)NTOK * CT * 4, hipMemcpyDeviceToDevice, stream);

    topk_kernel<<<NTOK / 4, 256, 0, stream>>>(X_L, idx);
    sprep_kernel<<<NTOK, 384, 0, stream>>>(S_I, aln1_sln_g, aln2_sln_g, S_bf, snb);
    biasprep_kernel<<<NBLK * 3072 / 256, 256, 0, stream>>>(bq, sg_b, tsg_b, qkvgbias, sgbias);

    // ---- one conversion launch for ALL blocks' weights ----
    {
        ConvTable tab;
        int p = 0, ts = 0;
        auto add = [&](const float* s, size_t dstOff, int Kk, int Nn, int sstride) {
            tab.e[p].src = s; tab.e[p].dst = Wbuf + dstOff; tab.e[p].K = Kk;
            tab.e[p].N = Nn; tab.e[p].tstart = ts; tab.e[p].srcStride = sstride;
            ts += (Kk / 32) * (Nn / 32); ++p;
        };
        add(aln1_sw,  OFF_A1SW,           384, 768,  CS * CT);
        add(aln1_shw, OFF_A1SHW,          384, 768,  CS * CT);
        add(Wq, OFF_QKVG + 0 * 589824,    768, 768,  CT * CT);
        add(Wk, OFF_QKVG + 1 * 589824,    768, 768,  CT * CT);
        add(Wv, OFF_QKVG + 2 * 589824,    768, 768,  CT * CT);
        add(Wg, OFF_QKVG + 3 * 589824,    768, 768,  CT * CT);
        add(Wo, OFF_WO,                   768, 768,  CT * CT);
        add(sg_w,  OFF_SGT,               384, 768,  CS * CT);
        add(tsg_w, OFF_SGT + 768 * 384,   384, 768,  CS * CT);
        add(aln2_sw,  OFF_A2SW,           384, 768,  CS * CT);
        add(aln2_shw, OFF_A2SHW,          384, 768,  CS * CT);
        add(t_w1, OFF_TW1,                768, 1536, CT * 2 * CT);
        add(t_w2, OFF_TW2,                768, 1536, CT * 2 * CT);
        add(t_w3, OFF_TW3,                1536, 768, 2 * CT * CT);
        convT_kernel<<<dim3(ts, NBLK), 256, 0, stream>>>(tab);
    }

    // ---- hoisted S-only GEMMs (grouped) ----
    gemm_kernel<5><<<dim3(12, 16, 8), 256, 0, stream>>>(
        snb, Wbuf, nullptr, aln1_sb, aln2_sb, nullptr, 0,
        nullptr, SIG, SH, 384, 768, 768);
    gemm_kernel<6><<<dim3(24, 16, 4), 256, 0, stream>>>(
        S_bf, Wbuf + OFF_SGT, nullptr, sgbias, nullptr, nullptr, 0,
        nullptr, sgateb, nullptr, 384, 1536, 1536);

    for (int i = 0; i < NBLK; ++i) {
        const __hip_bfloat16* Wb_i = Wbuf + (size_t)i * WS_BLK;
        __hip_bfloat16* sg_i = sgateb + (size_t)i * NTOK * 1536;

        // ---- LocalAttentionPairBias ----
        adaapply_kernel<<<NTOK, 256, 0, stream>>>(
            A, SIG + (size_t)(2 * i) * NTOK * CT, SH + (size_t)(2 * i) * NTOK * CT, an);
        gemm_kernel<4><<<dim3(48, 16), 256, 0, stream>>>(
            an, Wb_i + OFF_QKVG, nullptr, qkvgbias + (size_t)i * 3072, nullptr,
            nullptr, 0, nullptr, qkvg, nullptr, 768, 3072, 3072);
        attn_kernel<<<NTOK, 256, 0, stream>>>(
            qkvg, Z_II, idx, pair_ln_g + (size_t)i * CP, pair_ln_b + (size_t)i * CP,
            Wbp + (size_t)i * CP * NH, o2);
        gemm_kernel<3><<<dim3(12, 16), 256, 0, stream>>>(
            o2, Wb_i + OFF_WO, nullptr, nullptr, nullptr, sg_i, 1536,
            A, nullptr, nullptr, 768, 768, 768);

        // ---- ConditionedTransitionBlock ----
        adaapply_kernel<<<NTOK, 256, 0, stream>>>(
            A, SIG + (size_t)(2 * i + 1) * NTOK * CT, SH + (size_t)(2 * i + 1) * NTOK * CT, an);
        gemm_kernel<2><<<dim3(24, 16), 256, 0, stream>>>(
            an, Wb_i + OFF_TW1, Wb_i + OFF_TW2, nullptr, nullptr, nullptr, 0,
            nullptr, hb, nullptr, 768, 1536, 1536);
        gemm_kernel<3><<<dim3(12, 16), 256, 0, stream>>>(
            hb, Wb_i + OFF_TW3, nullptr, nullptr, nullptr, sg_i + 768, 1536,
            A, nullptr, nullptr, 1536, 768, 768);
    }
}